// Round 15
// baseline (762.252 us; speedup 1.0000x reference)
//
#include <hip/hip_runtime.h>

#define DI __device__ __forceinline__

namespace {

constexpr int kL  = 2048;
constexpr int kB  = 4;
constexpr int kE  = 512;
constexpr int kHD = 64;
constexpr int kFF = 2048;
constexpr int kNE = 5;
constexpr int kT  = 8192;   // kL * kB tokens
constexpr int kCAP = 4;

using bf16x8 = __attribute__((ext_vector_type(8))) short;
using f32x4  = __attribute__((ext_vector_type(4))) float;

DI float bf2f(unsigned short u) { return __uint_as_float(((unsigned)u) << 16); }
DI unsigned short f2bf(float f) {
  unsigned u = __float_as_uint(f);
  u = u + 0x7FFFu + ((u >> 16) & 1u);
  return (unsigned short)(u >> 16);
}

DI unsigned rotl(unsigned v, int d) { return (v << d) | (v >> (32 - d)); }

// JAX threefry2x32 with key = PRNGKey(42) = (0, 42), 20 rounds.
DI void threefry(unsigned& x0, unsigned& x1) {
  const unsigned K1 = 0u, K2 = 42u, K3 = 0x1BD11BDAu ^ 0u ^ 42u;
  x0 += K1; x1 += K2;
  x0 += x1; x1 = rotl(x1, 13); x1 ^= x0;
  x0 += x1; x1 = rotl(x1, 15); x1 ^= x0;
  x0 += x1; x1 = rotl(x1, 26); x1 ^= x0;
  x0 += x1; x1 = rotl(x1,  6); x1 ^= x0;
  x0 += K2; x1 += K3 + 1u;
  x0 += x1; x1 = rotl(x1, 17); x1 ^= x0;
  x0 += x1; x1 = rotl(x1, 29); x1 ^= x0;
  x0 += x1; x1 = rotl(x1, 16); x1 ^= x0;
  x0 += x1; x1 = rotl(x1, 24); x1 ^= x0;
  x0 += K3; x1 += K1 + 2u;
  x0 += x1; x1 = rotl(x1, 13); x1 ^= x0;
  x0 += x1; x1 = rotl(x1, 15); x1 ^= x0;
  x0 += x1; x1 = rotl(x1, 26); x1 ^= x0;
  x0 += x1; x1 = rotl(x1,  6); x1 ^= x0;
  x0 += K1; x1 += K2 + 3u;
  x0 += x1; x1 = rotl(x1, 17); x1 ^= x0;
  x0 += x1; x1 = rotl(x1, 29); x1 ^= x0;
  x0 += x1; x1 = rotl(x1, 16); x1 ^= x0;
  x0 += x1; x1 = rotl(x1, 24); x1 ^= x0;
  x0 += K2; x1 += K3 + 4u;
  x0 += x1; x1 = rotl(x1, 13); x1 ^= x0;
  x0 += x1; x1 = rotl(x1, 15); x1 ^= x0;
  x0 += x1; x1 = rotl(x1, 26); x1 ^= x0;
  x0 += x1; x1 = rotl(x1,  6); x1 ^= x0;
  x0 += K3; x1 += K1 + 5u;
}

// ---------------- f32 -> bf16 bulk convert -----------------------------------
__global__ __launch_bounds__(256) void f2bf_kernel(
    const float* __restrict__ src, unsigned short* __restrict__ dst, int n4) {
  int i = blockIdx.x * blockDim.x + threadIdx.x;
  if (i >= n4) return;
  float4 v = ((const float4*)src)[i];
  ushort4 u;
  u.x = f2bf(v.x); u.y = f2bf(v.y); u.z = f2bf(v.z); u.w = f2bf(v.w);
  ((ushort4*)dst)[i] = u;
}

// ---------------- LayerNorm (one row per block, 256 threads, E=512) -----------
__global__ __launch_bounds__(256) void ln_kernel(
    const float* __restrict__ x, const float* __restrict__ w,
    const float* __restrict__ b, float* __restrict__ out) {
  int row = blockIdx.x;
  const float* xr = x + (size_t)row * kE;
  int t = threadIdx.x;
  float2 v = *(const float2*)(xr + t * 2);
  __shared__ float red[4];
  float s = v.x + v.y;
  #pragma unroll
  for (int m = 32; m; m >>= 1) s += __shfl_xor(s, m);
  if ((t & 63) == 0) red[t >> 6] = s;
  __syncthreads();
  float mu = (red[0] + red[1] + red[2] + red[3]) * (1.0f / kE);
  float dx = v.x - mu, dy = v.y - mu;
  float q = dx * dx + dy * dy;
  #pragma unroll
  for (int m = 32; m; m >>= 1) q += __shfl_xor(q, m);
  __syncthreads();
  if ((t & 63) == 0) red[t >> 6] = q;
  __syncthreads();
  float var = (red[0] + red[1] + red[2] + red[3]) * (1.0f / kE);
  float inv = 1.0f / sqrtf(var + 1e-5f);
  float2 o;
  o.x = dx * inv * w[t * 2]     + b[t * 2];
  o.y = dy * inv * w[t * 2 + 1] + b[t * 2 + 1];
  *(float2*)(out + (size_t)row * kE + t * 2) = o;
}

// ---------------- 128x128 f32 GEMM, BT=1 (C=A*B^T), non-MOE ------------------
// SPLITOUT=1: write hi/lo bf16 split of the f32 result (for attention).
template <int BIAS, int RES, int SPLITOUT>
__global__ __launch_bounds__(256) void gemm_kernel(
    const float* __restrict__ Ap, const float* __restrict__ Bp,
    const float* __restrict__ biasp, const float* __restrict__ Rp,
    float* __restrict__ Cp, unsigned short* __restrict__ Chi,
    unsigned short* __restrict__ Clo, int M, int N, int K) {
  __shared__ float As[2][16][132];
  __shared__ float Bs[2][16][132];

  int nwg = gridDim.x * gridDim.y;
  int bid = blockIdx.y * gridDim.x + blockIdx.x;
  int swz = (bid & 7) * (nwg >> 3) + (bid >> 3);
  int wx = swz % gridDim.x, wy = swz / gridDim.x;

  const int m0 = wy * 128;
  const int n0 = wx * 128;
  const int t = threadIdx.x;
  const int tx = t & 15, ty = t >> 4;

  const int ar = t >> 2;
  const int ak = (t & 3) * 4;
  size_t arow0 = (size_t)(m0 + ar) * K + ak;
  size_t arow1 = (size_t)(m0 + ar + 64) * K + ak;
  const int b_r = t >> 2, b_o = (t & 3) * 4;

  float acc[8][8];
  #pragma unroll
  for (int i = 0; i < 8; ++i)
    #pragma unroll
    for (int j = 0; j < 8; ++j) acc[i][j] = 0.0f;

  float4 v0r, v1r, w0, w1v;
  auto load_tile = [&](int k0) {
    v0r = *(const float4*)(Ap + arow0 + k0);
    v1r = *(const float4*)(Ap + arow1 + k0);
    w0  = *(const float4*)(Bp + (size_t)(n0 + b_r) * K + k0 + b_o);
    w1v = *(const float4*)(Bp + (size_t)(n0 + b_r + 64) * K + k0 + b_o);
  };
  load_tile(0);

  for (int k0 = 0; k0 < K; k0 += 16) {
    const int bf = (k0 >> 4) & 1;
    As[bf][ak+0][ar] = v0r.x; As[bf][ak+1][ar] = v0r.y;
    As[bf][ak+2][ar] = v0r.z; As[bf][ak+3][ar] = v0r.w;
    As[bf][ak+0][ar+64] = v1r.x; As[bf][ak+1][ar+64] = v1r.y;
    As[bf][ak+2][ar+64] = v1r.z; As[bf][ak+3][ar+64] = v1r.w;
    Bs[bf][b_o+0][b_r] = w0.x; Bs[bf][b_o+1][b_r] = w0.y;
    Bs[bf][b_o+2][b_r] = w0.z; Bs[bf][b_o+3][b_r] = w0.w;
    Bs[bf][b_o+0][b_r+64] = w1v.x; Bs[bf][b_o+1][b_r+64] = w1v.y;
    Bs[bf][b_o+2][b_r+64] = w1v.z; Bs[bf][b_o+3][b_r+64] = w1v.w;
    __syncthreads();
    if (k0 + 16 < K) load_tile(k0 + 16);
    #pragma unroll
    for (int kk = 0; kk < 16; ++kk) {
      float av[8], bv[8];
      *(float4*)&av[0] = *(const float4*)&As[bf][kk][ty * 8];
      *(float4*)&av[4] = *(const float4*)&As[bf][kk][ty * 8 + 4];
      *(float4*)&bv[0] = *(const float4*)&Bs[bf][kk][tx * 4];
      *(float4*)&bv[4] = *(const float4*)&Bs[bf][kk][tx * 4 + 64];
      #pragma unroll
      for (int i = 0; i < 8; ++i)
        #pragma unroll
        for (int j = 0; j < 8; ++j)
          acc[i][j] = fmaf(av[i], bv[j], acc[i][j]);
    }
  }

  #pragma unroll
  for (int i = 0; i < 8; ++i) {
    int rloc = m0 + ty * 8 + i;
    size_t crow = (size_t)rloc * N;
    #pragma unroll
    for (int half = 0; half < 2; ++half) {
      int c = n0 + half * 64 + tx * 4;
      float v[4];
      #pragma unroll
      for (int j = 0; j < 4; ++j) {
        v[j] = acc[i][half * 4 + j];
        if (BIAS) v[j] += biasp[c + j];
        if (RES)  v[j] += Rp[crow + c + j];
      }
      if (SPLITOUT) {
        ushort4 hi4, lo4;
        unsigned short* hp = (unsigned short*)&hi4;
        unsigned short* lp = (unsigned short*)&lo4;
        #pragma unroll
        for (int j = 0; j < 4; ++j) {
          unsigned short hi = f2bf(v[j]);
          hp[j] = hi;
          lp[j] = f2bf(v[j] - bf2f(hi));
        }
        *(ushort4*)(Chi + crow + c) = hi4;
        *(ushort4*)(Clo + crow + c) = lo4;
      } else {
        *(float4*)(Cp + crow + c) = make_float4(v[0], v[1], v[2], v[3]);
      }
    }
  }
}

// ---------------- MoE bf16 MFMA GEMM (unchanged, verified r11) ---------------
template <int GATHER, int RELU, int K, int N>
__global__ __launch_bounds__(256) void moe_mfma_kernel(
    const unsigned short* __restrict__ Abf, const unsigned short* __restrict__ Bbf,
    unsigned short* __restrict__ Cbf,
    const int* __restrict__ gatherp, const int* __restrict__ cntp,
    const int* __restrict__ basep) {
  __shared__ unsigned short As[128][40];
  __shared__ unsigned short Bs[128][40];

  const int e = blockIdx.z;
  const int M = cntp[e];
  const int rowOff = basep[e];
  if ((int)blockIdx.y * 128 >= M) return;
  const unsigned short* Bg = Bbf + (size_t)e * K * N;
  const int m0 = blockIdx.y * 128;
  const int n0 = blockIdx.x * 128;
  const int t = threadIdx.x;
  const int lane = t & 63, w = t >> 6;
  const int wm = w >> 1, wn = w & 1;

  const int ar = t >> 1, ah = t & 1;
  size_t abase;
  {
    int r = m0 + ar;
    int mm = M - 1; r = r < mm ? r : mm;
    if (GATHER) r = gatherp[rowOff + r];
    else        r += rowOff;
    abase = (size_t)r * K;
  }
  const int bk = t >> 3, bn = (t & 7) * 16;

  f32x4 acc[4][4];
  #pragma unroll
  for (int i = 0; i < 4; ++i)
    #pragma unroll
    for (int j = 0; j < 4; ++j)
      acc[i][j] = (f32x4){0.f, 0.f, 0.f, 0.f};

  uint4 aR0, aR1, bR0, bR1;
  auto gload = [&](int k0) {
    aR0 = *(const uint4*)(Abf + abase + k0 + ah * 16);
    aR1 = *(const uint4*)(Abf + abase + k0 + ah * 16 + 8);
    bR0 = *(const uint4*)(Bg + (size_t)(k0 + bk) * N + n0 + bn);
    bR1 = *(const uint4*)(Bg + (size_t)(k0 + bk) * N + n0 + bn + 8);
  };
  gload(0);

  const int kg = (lane >> 4) * 8;
  const int mr = lane & 15;

  for (int k0 = 0; k0 < K; k0 += 32) {
    __syncthreads();
    *(uint4*)&As[ar][ah * 16]     = aR0;
    *(uint4*)&As[ar][ah * 16 + 8] = aR1;
    {
      unsigned short tmp[16];
      *(uint4*)tmp       = bR0;
      *(uint4*)(tmp + 8) = bR1;
      #pragma unroll
      for (int j = 0; j < 16; ++j) Bs[bn + j][bk] = tmp[j];
    }
    __syncthreads();
    if (k0 + 32 < K) gload(k0 + 32);

    bf16x8 af[4], bfr[4];
    #pragma unroll
    for (int i = 0; i < 4; ++i)
      af[i] = *(const bf16x8*)&As[wm * 64 + i * 16 + mr][kg];
    #pragma unroll
    for (int j = 0; j < 4; ++j)
      bfr[j] = *(const bf16x8*)&Bs[wn * 64 + j * 16 + mr][kg];
    #pragma unroll
    for (int i = 0; i < 4; ++i)
      #pragma unroll
      for (int j = 0; j < 4; ++j)
        acc[i][j] = __builtin_amdgcn_mfma_f32_16x16x32_bf16(
            af[i], bfr[j], acc[i][j], 0, 0, 0);
  }

  const int lr4 = (lane >> 4) * 4;
  const int lc = lane & 15;
  #pragma unroll
  for (int i = 0; i < 4; ++i)
    #pragma unroll
    for (int r = 0; r < 4; ++r) {
      int row = m0 + wm * 64 + i * 16 + lr4 + r;
      if (row >= M) continue;
      size_t crow = (size_t)(row + rowOff) * N;
      #pragma unroll
      for (int j = 0; j < 4; ++j) {
        float v = acc[i][j][r];
        if (RELU) v = v > 0.f ? v : 0.f;
        Cbf[crow + n0 + wn * 64 + j * 16 + lc] = f2bf(v);
      }
    }
}

// ---------------- Flash attention: split-bf16 MFMA, PRE-SPLIT K/V/Q ----------
// qkv comes pre-split (hi/lo bf16) from the QKV GEMM epilogue -> staging is
// pure u16 copies, no per-tile conversions. Scores scaled by 0.125 post-MFMA
// (exact). P split per tile (computed here). K/P alias; 4 barriers/tile.
DI int pswz(int row) { return ((row >> 1) & 7) << 3; }

__global__ __launch_bounds__(256) void flash_kernel(
    const unsigned short* __restrict__ qh, const unsigned short* __restrict__ ql,
    float* __restrict__ attn_out) {
  __shared__ unsigned short KPhi[64][72];   // K during QK; P during PV
  __shared__ unsigned short KPlo[64][72];
  __shared__ unsigned short Vthi[64][72];   // V^T: [d][kv]
  __shared__ unsigned short Vtlo[64][72];

  int bid = blockIdx.y * 32 + blockIdx.x;   // grid (32, 32)
  int swzb = (bid & 7) * 128 + (bid >> 3);
  const int bh = swzb >> 5;
  const int qt = swzb & 31;
  const int b = bh >> 3, h = bh & 7;
  const int t = threadIdx.x;
  const int w = t >> 6, lane = t & 63;
  const int l15 = lane & 15, l4 = lane >> 4;
  const int lr = t >> 2;             // K-staging row 0..63
  const int dbase = (t & 3) * 16;    // K-staging d offset
  const int vd = t & 63;             // V-staging column (d)
  const int kv0 = (t >> 6) * 16;     // V-staging kv block

  // Q A-fragments (unscaled; 0.125 applied to scores post-MFMA, exact)
  bf16x8 qhi[2], qlo[2];
  {
    int qglob = qt * 64 + w * 16 + l15;
    size_t qoff = ((size_t)(qglob * kB + b)) * (3 * kE) + h * kHD;
    #pragma unroll
    for (int ks = 0; ks < 2; ++ks) {
      qhi[ks] = *(const bf16x8*)(qh + qoff + ks * 32 + l4 * 8);
      qlo[ks] = *(const bf16x8*)(ql + qoff + ks * 32 + l4 * 8);
    }
  }

  float m_i[4], l_i[4];
  f32x4 Oacc[4];                     // [df]; element r -> q-row w*16+l4*4+r
  #pragma unroll
  for (int r = 0; r < 4; ++r) { m_i[r] = -1e30f; l_i[r] = 0.f; }
  #pragma unroll
  for (int df = 0; df < 4; ++df) Oacc[df] = (f32x4){0.f, 0.f, 0.f, 0.f};

  uint4 kh[2], kl[2];
  unsigned short vh[16], vl[16];
  auto kv_load = [&](int ktile) {
    size_t koff = ((size_t)((ktile * 64 + lr) * kB + b)) * (3 * kE) + kE + h * kHD + dbase;
    kh[0] = *(const uint4*)(qh + koff);
    kh[1] = *(const uint4*)(qh + koff + 8);
    kl[0] = *(const uint4*)(ql + koff);
    kl[1] = *(const uint4*)(ql + koff + 8);
    #pragma unroll
    for (int j = 0; j < 16; ++j) {
      size_t voff = ((size_t)((ktile * 64 + kv0 + j) * kB + b)) * (3 * kE) + 2 * kE + h * kHD + vd;
      vh[j] = qh[voff];
      vl[j] = ql[voff];
    }
  };
  kv_load(0);

  for (int kt = 0; kt < 32; ++kt) {
    __syncthreads();                 // barA: prev tile's PV reads done
    {
      int sw = pswz(lr);
      *(uint4*)&KPhi[lr][(dbase)     ^ sw] = kh[0];
      *(uint4*)&KPhi[lr][(dbase + 8) ^ sw] = kh[1];
      *(uint4*)&KPlo[lr][(dbase)     ^ sw] = kl[0];
      *(uint4*)&KPlo[lr][(dbase + 8) ^ sw] = kl[1];
      int swv = pswz(vd);
      *(uint4*)&Vthi[vd][(kv0)     ^ swv] = ((uint4*)vh)[0];
      *(uint4*)&Vthi[vd][(kv0 + 8) ^ swv] = ((uint4*)vh)[1];
      *(uint4*)&Vtlo[vd][(kv0)     ^ swv] = ((uint4*)vl)[0];
      *(uint4*)&Vtlo[vd][(kv0 + 8) ^ swv] = ((uint4*)vl)[1];
    }
    __syncthreads();                 // barB: K/V staged
    if (kt + 1 < 32) kv_load(kt + 1);

    // QK^T: split-bf16 MFMA; acc[nf] -> kv cols nf*16+l15, q rows l4*4+r
    f32x4 acc[4];
    #pragma unroll
    for (int nf = 0; nf < 4; ++nf) acc[nf] = (f32x4){0.f, 0.f, 0.f, 0.f};
    #pragma unroll
    for (int ks = 0; ks < 2; ++ks) {
      #pragma unroll
      for (int nf = 0; nf < 4; ++nf) {
        int krow = nf * 16 + l15;
        int off = (ks * 32 + l4 * 8) ^ pswz(krow);
        bf16x8 kkh = *(const bf16x8*)&KPhi[krow][off];
        bf16x8 kkl = *(const bf16x8*)&KPlo[krow][off];
        acc[nf] = __builtin_amdgcn_mfma_f32_16x16x32_bf16(qhi[ks], kkh, acc[nf], 0, 0, 0);
        acc[nf] = __builtin_amdgcn_mfma_f32_16x16x32_bf16(qhi[ks], kkl, acc[nf], 0, 0, 0);
        acc[nf] = __builtin_amdgcn_mfma_f32_16x16x32_bf16(qlo[ks], kkh, acc[nf], 0, 0, 0);
      }
    }
    // apply 1/8 scale (exact power of 2; bit-identical to scaling Q inputs)
    #pragma unroll
    for (int nf = 0; nf < 4; ++nf)
      #pragma unroll
      for (int r = 0; r < 4; ++r) acc[nf][r] *= 0.125f;

    // online softmax in C-layout; O-rescale lane-local
    float pv[4][4];
    float alpha[4];
    #pragma unroll
    for (int r = 0; r < 4; ++r) {
      float tm = fmaxf(fmaxf(acc[0][r], acc[1][r]), fmaxf(acc[2][r], acc[3][r]));
      #pragma unroll
      for (int m = 1; m < 16; m <<= 1) tm = fmaxf(tm, __shfl_xor(tm, m));
      float mn = fmaxf(m_i[r], tm);
      alpha[r] = __expf(m_i[r] - mn);
      m_i[r] = mn;
      float rs = 0.f;
      #pragma unroll
      for (int nf = 0; nf < 4; ++nf) {
        float p = __expf(acc[nf][r] - mn);
        pv[r][nf] = p;
        rs += p;
      }
      #pragma unroll
      for (int m = 1; m < 16; m <<= 1) rs += __shfl_xor(rs, m);
      l_i[r] = l_i[r] * alpha[r] + rs;
    }
    #pragma unroll
    for (int df = 0; df < 4; ++df)
      #pragma unroll
      for (int r = 0; r < 4; ++r) Oacc[df][r] *= alpha[r];

    __syncthreads();                 // barC: K reads done; buffers free for P
    #pragma unroll
    for (int r = 0; r < 4; ++r) {
      int qrow = w * 16 + l4 * 4 + r;
      int sw = pswz(qrow);
      #pragma unroll
      for (int nf = 0; nf < 4; ++nf) {
        int scol = (nf * 16 + l15) ^ sw;
        float p = pv[r][nf];
        unsigned short hi = f2bf(p);
        KPhi[qrow][scol] = hi;
        KPlo[qrow][scol] = f2bf(p - bf2f(hi));
      }
    }
    __syncthreads();                 // barD: P visible

    // PV: split-bf16 MFMA; A = P [qrow][kv], B = V^T [d][kv]
    {
      int prow = w * 16 + l15;
      int swp = pswz(prow);
      #pragma unroll
      for (int ks = 0; ks < 2; ++ks) {
        int koff = ks * 32 + l4 * 8;
        bf16x8 ph = *(const bf16x8*)&KPhi[prow][koff ^ swp];
        bf16x8 pl = *(const bf16x8*)&KPlo[prow][koff ^ swp];
        #pragma unroll
        for (int df = 0; df < 4; ++df) {
          int vrow = df * 16 + l15;
          int off = koff ^ pswz(vrow);
          bf16x8 vvh = *(const bf16x8*)&Vthi[vrow][off];
          bf16x8 vvl = *(const bf16x8*)&Vtlo[vrow][off];
          Oacc[df] = __builtin_amdgcn_mfma_f32_16x16x32_bf16(ph, vvh, Oacc[df], 0, 0, 0);
          Oacc[df] = __builtin_amdgcn_mfma_f32_16x16x32_bf16(ph, vvl, Oacc[df], 0, 0, 0);
          Oacc[df] = __builtin_amdgcn_mfma_f32_16x16x32_bf16(pl, vvh, Oacc[df], 0, 0, 0);
        }
      }
    }
  }

  // output: row = qt*64 + w*16 + l4*4 + r, col = h*64 + df*16 + l15
  #pragma unroll
  for (int r = 0; r < 4; ++r) {
    float inv = 1.0f / l_i[r];
    int l = qt * 64 + w * 16 + l4 * 4 + r;
    float* orow = attn_out + ((size_t)(l * kB + b)) * kE + h * kHD;
    #pragma unroll
    for (int df = 0; df < 4; ++df)
      orow[df * 16 + l15] = Oacc[df][r] * inv;
  }
}

// ---------------- Gating: logits, softmax, top2, partitionable-XOR threefry --
__global__ __launch_bounds__(256) void gating_kernel(
    const float* __restrict__ h2, const float* __restrict__ wg,
    int* __restrict__ e1, int* __restrict__ e2,
    float* __restrict__ g1, float* __restrict__ g2,
    int* __restrict__ keepr) {
  __shared__ float swg[kE * kNE];
  for (int i = threadIdx.x; i < kE * kNE; i += 256) swg[i] = wg[i];
  __syncthreads();
  int w = threadIdx.x >> 6, lane = threadIdx.x & 63;
  int tok = blockIdx.x * 4 + w;
  const float* xr = h2 + (size_t)tok * kE;
  float a0=0,a1=0,a2=0,a3=0,a4=0;
  for (int d = lane; d < kE; d += 64) {
    float xv = xr[d];
    a0 = fmaf(xv, swg[d*5+0], a0);
    a1 = fmaf(xv, swg[d*5+1], a1);
    a2 = fmaf(xv, swg[d*5+2], a2);
    a3 = fmaf(xv, swg[d*5+3], a3);
    a4 = fmaf(xv, swg[d*5+4], a4);
  }
  #pragma unroll
  for (int m = 32; m; m >>= 1) {
    a0 += __shfl_xor(a0, m); a1 += __shfl_xor(a1, m); a2 += __shfl_xor(a2, m);
    a3 += __shfl_xor(a3, m); a4 += __shfl_xor(a4, m);
  }
  if (lane == 0) {
    float lg[5] = {a0, a1, a2, a3, a4};
    float mx = lg[0];
    #pragma unroll
    for (int e = 1; e < 5; ++e) mx = fmaxf(mx, lg[e]);
    float ex[5], ssum = 0.f;
    #pragma unroll
    for (int e = 0; e < 5; ++e) { ex[e] = expf(lg[e] - mx); ssum += ex[e]; }
    float raw[5];
    #pragma unroll
    for (int e = 0; e < 5; ++e) raw[e] = ex[e] / ssum;
    int i1 = 0; float v1 = raw[0];
    #pragma unroll
    for (int e = 1; e < 5; ++e) if (raw[e] > v1) { v1 = raw[e]; i1 = e; }
    int i2 = 0; float v2 = -1.f;
    #pragma unroll
    for (int e = 0; e < 5; ++e) if (e != i1 && raw[e] > v2) { v2 = raw[e]; i2 = e; }
    float denom = v1 + v2 + 1e-9f;
    float G1 = v1 / denom, G2 = v2 / denom;
    unsigned x0 = 0u, x1 = (unsigned)tok;
    threefry(x0, x1);
    unsigned bits = x0 ^ x1;
    float u = __uint_as_float((bits >> 9) | 0x3F800000u) - 1.0f;
    int kr = (u < G2 / 0.2f) ? 1 : 0;
    e1[tok] = i1; e2[tok] = i2; g1[tok] = G1; g2[tok] = G2; keepr[tok] = kr;
  }
}

// ---------------- Per-group plan: positions + capacity -----------------------
__global__ __launch_bounds__(256) void plan_kernel(
    const int* __restrict__ e1, const int* __restrict__ e2,
    const int* __restrict__ keepr,
    int* __restrict__ slot1, int* __restrict__ slot2, int* __restrict__ tot) {
  int l = blockIdx.x * blockDim.x + threadIdx.x;
  if (l >= kL) return;
  int base = l * 4;
  int e1v[4], e2v[4], kr[4];
  #pragma unroll
  for (int n = 0; n < 4; ++n) {
    e1v[n] = e1[base + n]; e2v[n] = e2[base + n]; kr[n] = keepr[base + n];
  }
  int c1[5] = {0,0,0,0,0};
  int s1[4];
  #pragma unroll
  for (int n = 0; n < 4; ++n) {
    int e = e1v[n];
    int p = 0;
    #pragma unroll
    for (int q = 0; q < 5; ++q) if (q == e) p = c1[q];
    s1[n] = p;
    #pragma unroll
    for (int q = 0; q < 5; ++q) c1[q] += (q == e);
  }
  int run[5] = {0,0,0,0,0};
  int s2[4];
  #pragma unroll
  for (int n = 0; n < 4; ++n) {
    s2[n] = -1;
    if (kr[n]) {
      int e = e2v[n];
      int p = 0;
      #pragma unroll
      for (int q = 0; q < 5; ++q) if (q == e) p = c1[q] + run[q];
      if (p < kCAP) s2[n] = p;
      #pragma unroll
      for (int q = 0; q < 5; ++q) run[q] += (q == e);
    }
  }
  #pragma unroll
  for (int n = 0; n < 4; ++n) { slot1[base + n] = s1[n]; slot2[base + n] = s2[n]; }
  int adm[5] = {0,0,0,0,0};
  #pragma unroll
  for (int n = 0; n < 4; ++n)
    if (s2[n] >= 0) {
      #pragma unroll
      for (int q = 0; q < 5; ++q) adm[q] += (q == e2v[n]);
    }
  #pragma unroll
  for (int q = 0; q < 5; ++q) tot[l * kNE + q] = c1[q] + adm[q];
}

// ---------------- Per-expert exclusive scan of group totals ------------------
__global__ __launch_bounds__(256) void scan_kernel(
    const int* __restrict__ tot, int* __restrict__ gbase, int* __restrict__ cnt) {
  int e = blockIdx.x;
  int t = threadIdx.x;
  int lane = t & 63, w = t >> 6;
  __shared__ int wsum[4];
  __shared__ int carry;
  if (t == 0) carry = 0;
  __syncthreads();
  for (int chunk = 0; chunk < kL / 256; ++chunk) {
    int g = chunk * 256 + t;
    int v = tot[g * kNE + e];
    int inc = v;
    #pragma unroll
    for (int off = 1; off < 64; off <<= 1) {
      int u = __shfl_up(inc, off);
      if (lane >= off) inc += u;
    }
    if (lane == 63) wsum[w] = inc;
    __syncthreads();
    int wb = 0;
    #pragma unroll
    for (int i = 0; i < 4; ++i) wb += (i < w) ? wsum[i] : 0;
    int total = wsum[0] + wsum[1] + wsum[2] + wsum[3];
    gbase[g * kNE + e] = carry + wb + inc - v;
    __syncthreads();
    if (t == 0) carry += total;
    __syncthreads();
  }
  if (t == 0) cnt[e] = carry;
}

__global__ void bases_kernel(const int* __restrict__ cnt, int* __restrict__ base) {
  if (threadIdx.x == 0 && blockIdx.x == 0) {
    int a = 0;
    #pragma unroll
    for (int e = 0; e < kNE; ++e) { base[e] = a; a += cnt[e]; }
  }
}

// ---------------- Row map: token -> expert-buffer rows -----------------------
__global__ __launch_bounds__(256) void rowmap_kernel(
    const int* __restrict__ e1, const int* __restrict__ e2,
    const int* __restrict__ slot1, const int* __restrict__ slot2,
    const int* __restrict__ gbase, const int* __restrict__ ebase,
    int* __restrict__ rowOf1, int* __restrict__ rowOf2,
    int* __restrict__ tokOfRow) {
  int tok = blockIdx.x * blockDim.x + threadIdx.x;
  if (tok >= kT) return;
  int l = tok >> 2;
  int a = e1[tok];
  int r1 = ebase[a] + gbase[l * kNE + a] + slot1[tok];
  rowOf1[tok] = r1;
  tokOfRow[r1] = tok;
  int s2 = slot2[tok];
  int r2 = -1;
  if (s2 >= 0) {
    int bq = e2[tok];
    r2 = ebase[bq] + gbase[l * kNE + bq] + s2;
    tokOfRow[r2] = tok;
  }
  rowOf2[tok] = r2;
}

// ---------------- Final combine: out = x_res + g1*eo[r1] + g2*eo[r2] ---------
__global__ __launch_bounds__(128) void combine_kernel(
    const float* __restrict__ xres, const unsigned short* __restrict__ eo,
    const float* __restrict__ g1, const float* __restrict__ g2,
    const int* __restrict__ rowOf1, const int* __restrict__ rowOf2,
    float* __restrict__ out) {
  int tok = blockIdx.x;
  int t = threadIdx.x;
  float4 o = *(const float4*)(xres + (size_t)tok * kE + t * 4);
  int p1 = rowOf1[tok];
  float G1 = g1[tok];
  ushort4 a = *(const ushort4*)(eo + (size_t)p1 * kE + t * 4);
  o.x += G1 * bf2f(a.x); o.y += G1 * bf2f(a.y);
  o.z += G1 * bf2f(a.z); o.w += G1 * bf2f(a.w);
  int p2 = rowOf2[tok];
  if (p2 >= 0) {
    float G2 = g2[tok];
    ushort4 c = *(const ushort4*)(eo + (size_t)p2 * kE + t * 4);
    o.x += G2 * bf2f(c.x); o.y += G2 * bf2f(c.y);
    o.z += G2 * bf2f(c.z); o.w += G2 * bf2f(c.w);
  }
  *(float4*)(out + (size_t)tok * kE + t * 4) = o;
}

}  // namespace

extern "C" void kernel_launch(void* const* d_in, const int* in_sizes, int n_in,
                              void* d_out, int out_size, void* d_ws, size_t ws_size,
                              hipStream_t stream) {
  (void)in_sizes; (void)n_in; (void)out_size;
  const float* x    = (const float*)d_in[0];
  const float* ln1w = (const float*)d_in[1];
  const float* ln1b = (const float*)d_in[2];
  const float* ln2w = (const float*)d_in[3];
  const float* ln2b = (const float*)d_in[4];
  const float* wqkv = (const float*)d_in[5];
  const float* bqkv = (const float*)d_in[6];
  const float* wo   = (const float*)d_in[7];
  const float* bo   = (const float*)d_in[8];
  const float* wg   = (const float*)d_in[9];
  const float* w1   = (const float*)d_in[10];
  const float* w2   = (const float*)d_in[11];
  float* out = (float*)d_out;

  // ws layout (float units), 33.75M floats:
  // [0,        4194304)   xres f32
  // [4194304,  10485760)  qkvhi u16 (8192x1536)   } dead after flash;
  // [10485760, 16777216)  qkvlo u16               } region [4194304,20971520)
  // [16777216, 20971520)  h1 f32 (attn out)       } reused as hmoe bf16
  // [20971520, 25165824)  h2 f32 -> eo bf16 after gating
  // [25165824, 27262976)  h2bf
  // [27262976, 29884416)  w1bf
  // [29884416, 32505856)  w2bf
  // [32505856, ...)       int buffers
  if (ws_size < (size_t)135000000) return;
  float* ws   = (float*)d_ws;
  float* xres = ws;
  unsigned short* qkvhi = (unsigned short*)(ws + 4194304);
  unsigned short* qkvlo = (unsigned short*)(ws + 10485760);
  unsigned short* hmoe  = (unsigned short*)(ws + 4194304);  // overlap (dead)
  float* h1   = ws + 16777216;
  float* h2   = ws + 20971520;
  unsigned short* eobf = (unsigned short*)(ws + 20971520);
  unsigned short* h2bf = (unsigned short*)(ws + 25165824);
  unsigned short* w1bf = (unsigned short*)(ws + 27262976);
  unsigned short* w2bf = (unsigned short*)(ws + 29884416);
  int* ibuf    = (int*)(ws + 32505856);
  int* e1      = ibuf;
  int* e2      = e1 + kT;
  float* g1f   = (float*)(e2 + kT);
  float* g2f   = g1f + kT;
  int* keepr   = (int*)(g2f + kT);
  int* slot1   = keepr + kT;
  int* slot2   = slot1 + kT;
  int* rowOf1  = slot2 + kT;
  int* rowOf2  = rowOf1 + kT;
  int* tot     = rowOf2 + kT;
  int* gbase   = tot + kL * kNE;
  int* tokOfRow= gbase + kL * kNE;
  int* cnt     = tokOfRow + 2 * kT;
  int* ebase   = cnt + 8;

  // 0. weights -> bf16
  f2bf_kernel<<<5120, 256, 0, stream>>>(w1, w1bf, kNE * kE * kFF / 4);
  f2bf_kernel<<<5120, 256, 0, stream>>>(w2, w2bf, kNE * kFF * kE / 4);
  // 1. h1 = LN1(x)
  ln_kernel<<<kT, 256, 0, stream>>>(x, ln1w, ln1b, h1);
  // 2. qkv = h1 @ Wqkv^T + b -> pre-split hi/lo bf16
  gemm_kernel<1,0,1><<<dim3(12, 64, 1), 256, 0, stream>>>(
      h1, wqkv, bqkv, nullptr, nullptr, qkvhi, qkvlo, kT, 1536, kE);
  // 3. attention (split-bf16 MFMA, pre-split operands), writes into h1
  flash_kernel<<<dim3(32, 32, 1), 256, 0, stream>>>(qkvhi, qkvlo, h1);
  // 4. x_res = x + attn_out @ Wo^T + bo
  gemm_kernel<1,1,0><<<dim3(4, 64, 1), 256, 0, stream>>>(
      h1, wo, bo, x, xres, nullptr, nullptr, kT, kE, kE);
  // 5. h2 = LN2(x_res)
  ln_kernel<<<kT, 256, 0, stream>>>(xres, ln2w, ln2b, h2);
  // 6. gating per token
  gating_kernel<<<kL, 256, 0, stream>>>(h2, wg, e1, e2, g1f, g2f, keepr);
  // 6b. h2 -> bf16
  f2bf_kernel<<<4096, 256, 0, stream>>>(h2, h2bf, kT * kE / 4);
  // 7. per-group plan
  plan_kernel<<<kL / 256, 256, 0, stream>>>(e1, e2, keepr, slot1, slot2, tot);
  // 8. per-expert scan; bases; row maps
  scan_kernel<<<kNE, 256, 0, stream>>>(tot, gbase, cnt);
  bases_kernel<<<1, 32, 0, stream>>>(cnt, ebase);
  rowmap_kernel<<<kT / 256, 256, 0, stream>>>(
      e1, e2, slot1, slot2, gbase, ebase, rowOf1, rowOf2, tokOfRow);
  // 9. hmoe = relu(gather(h2bf) @ w1bf[e])
  moe_mfma_kernel<1,1,kE,kFF><<<dim3(16, 64, kNE), 256, 0, stream>>>(
      h2bf, w1bf, hmoe, tokOfRow, cnt, ebase);
  // 10. eo = hmoe @ w2bf[e]
  moe_mfma_kernel<0,0,kFF,kE><<<dim3(4, 64, kNE), 256, 0, stream>>>(
      hmoe, w2bf, eobf, nullptr, cnt, ebase);
  // 11. out = x_res + g1*eo + g2*eo
  combine_kernel<<<kT, 128, 0, stream>>>(
      xres, eobf, g1f, g2f, rowOf1, rowOf2, out);
}

// Round 17
// 719.298 us; speedup vs baseline: 1.0597x; 1.0597x over previous
//
#include <hip/hip_runtime.h>

#define DI __device__ __forceinline__

namespace {

constexpr int kL  = 2048;
constexpr int kB  = 4;
constexpr int kE  = 512;
constexpr int kHD = 64;
constexpr int kFF = 2048;
constexpr int kNE = 5;
constexpr int kT  = 8192;   // kL * kB tokens
constexpr int kCAP = 4;

using bf16x8 = __attribute__((ext_vector_type(8))) short;
using f32x4  = __attribute__((ext_vector_type(4))) float;

DI float bf2f(unsigned short u) { return __uint_as_float(((unsigned)u) << 16); }
DI unsigned short f2bf(float f) {
  unsigned u = __float_as_uint(f);
  u = u + 0x7FFFu + ((u >> 16) & 1u);
  return (unsigned short)(u >> 16);
}

DI unsigned rotl(unsigned v, int d) { return (v << d) | (v >> (32 - d)); }

// JAX threefry2x32 with key = PRNGKey(42) = (0, 42), 20 rounds.
DI void threefry(unsigned& x0, unsigned& x1) {
  const unsigned K1 = 0u, K2 = 42u, K3 = 0x1BD11BDAu ^ 0u ^ 42u;
  x0 += K1; x1 += K2;
  x0 += x1; x1 = rotl(x1, 13); x1 ^= x0;
  x0 += x1; x1 = rotl(x1, 15); x1 ^= x0;
  x0 += x1; x1 = rotl(x1, 26); x1 ^= x0;
  x0 += x1; x1 = rotl(x1,  6); x1 ^= x0;
  x0 += K2; x1 += K3 + 1u;
  x0 += x1; x1 = rotl(x1, 17); x1 ^= x0;
  x0 += x1; x1 = rotl(x1, 29); x1 ^= x0;
  x0 += x1; x1 = rotl(x1, 16); x1 ^= x0;
  x0 += x1; x1 = rotl(x1, 24); x1 ^= x0;
  x0 += K3; x1 += K1 + 2u;
  x0 += x1; x1 = rotl(x1, 13); x1 ^= x0;
  x0 += x1; x1 = rotl(x1, 15); x1 ^= x0;
  x0 += x1; x1 = rotl(x1, 26); x1 ^= x0;
  x0 += x1; x1 = rotl(x1,  6); x1 ^= x0;
  x0 += K1; x1 += K2 + 3u;
  x0 += x1; x1 = rotl(x1, 17); x1 ^= x0;
  x0 += x1; x1 = rotl(x1, 29); x1 ^= x0;
  x0 += x1; x1 = rotl(x1, 16); x1 ^= x0;
  x0 += x1; x1 = rotl(x1, 24); x1 ^= x0;
  x0 += K2; x1 += K3 + 4u;
  x0 += x1; x1 = rotl(x1, 13); x1 ^= x0;
  x0 += x1; x1 = rotl(x1, 15); x1 ^= x0;
  x0 += x1; x1 = rotl(x1, 26); x1 ^= x0;
  x0 += x1; x1 = rotl(x1,  6); x1 ^= x0;
  x0 += K3; x1 += K1 + 5u;
}

// ---------------- f32 -> bf16 bulk convert -----------------------------------
__global__ __launch_bounds__(256) void f2bf_kernel(
    const float* __restrict__ src, unsigned short* __restrict__ dst, int n4) {
  int i = blockIdx.x * blockDim.x + threadIdx.x;
  if (i >= n4) return;
  float4 v = ((const float4*)src)[i];
  ushort4 u;
  u.x = f2bf(v.x); u.y = f2bf(v.y); u.z = f2bf(v.z); u.w = f2bf(v.w);
  ((ushort4*)dst)[i] = u;
}

// ---------------- f32 -> split hi/lo bf16 bulk -------------------------------
__global__ __launch_bounds__(256) void wsplit_kernel(
    const float* __restrict__ src, unsigned short* __restrict__ hi,
    unsigned short* __restrict__ lo, int n4) {
  int i = blockIdx.x * blockDim.x + threadIdx.x;
  if (i >= n4) return;
  float4 v = ((const float4*)src)[i];
  float va[4] = {v.x, v.y, v.z, v.w};
  ushort4 h4, l4;
  unsigned short* hp = (unsigned short*)&h4;
  unsigned short* lp = (unsigned short*)&l4;
  #pragma unroll
  for (int j = 0; j < 4; ++j) {
    unsigned short h = f2bf(va[j]);
    hp[j] = h;
    lp[j] = f2bf(va[j] - bf2f(h));
  }
  ((ushort4*)hi)[i] = h4;
  ((ushort4*)lo)[i] = l4;
}

// ---------------- LayerNorm; SPLIT=1 writes hi/lo bf16 -----------------------
template <int SPLIT>
__global__ __launch_bounds__(256) void ln_kernel(
    const float* __restrict__ x, const float* __restrict__ w,
    const float* __restrict__ b, float* __restrict__ out,
    unsigned short* __restrict__ ohi, unsigned short* __restrict__ olo) {
  int row = blockIdx.x;
  const float* xr = x + (size_t)row * kE;
  int t = threadIdx.x;
  float2 v = *(const float2*)(xr + t * 2);
  __shared__ float red[4];
  float s = v.x + v.y;
  #pragma unroll
  for (int m = 32; m; m >>= 1) s += __shfl_xor(s, m);
  if ((t & 63) == 0) red[t >> 6] = s;
  __syncthreads();
  float mu = (red[0] + red[1] + red[2] + red[3]) * (1.0f / kE);
  float dx = v.x - mu, dy = v.y - mu;
  float q = dx * dx + dy * dy;
  #pragma unroll
  for (int m = 32; m; m >>= 1) q += __shfl_xor(q, m);
  __syncthreads();
  if ((t & 63) == 0) red[t >> 6] = q;
  __syncthreads();
  float var = (red[0] + red[1] + red[2] + red[3]) * (1.0f / kE);
  float inv = 1.0f / sqrtf(var + 1e-5f);
  float ox = dx * inv * w[t * 2]     + b[t * 2];
  float oy = dy * inv * w[t * 2 + 1] + b[t * 2 + 1];
  if (SPLIT) {
    size_t base = (size_t)row * kE + t * 2;
    unsigned short hx = f2bf(ox), hy = f2bf(oy);
    ohi[base] = hx; ohi[base + 1] = hy;
    olo[base] = f2bf(ox - bf2f(hx)); olo[base + 1] = f2bf(oy - bf2f(hy));
  } else {
    *(float2*)(out + (size_t)row * kE + t * 2) = make_float2(ox, oy);
  }
}

// ---------------- Dense split-bf16 MFMA GEMM: C = A*B^T (+bias)(+R) ----------
template <int RES, int SPLITOUT>
__global__ __launch_bounds__(256) void dsgemm_kernel(
    const unsigned short* __restrict__ Ahi, const unsigned short* __restrict__ Alo,
    const unsigned short* __restrict__ Bhi, const unsigned short* __restrict__ Blo,
    const float* __restrict__ biasp, const float* __restrict__ Rp,
    float* __restrict__ Cf, unsigned short* __restrict__ Chi,
    unsigned short* __restrict__ Clo, int M, int N, int K) {
  __shared__ unsigned short AHs[128][40];
  __shared__ unsigned short ALs[128][40];
  __shared__ unsigned short BHs[128][40];
  __shared__ unsigned short BLs[128][40];

  int nwg = gridDim.x * gridDim.y;
  int bid = blockIdx.y * gridDim.x + blockIdx.x;
  int swz = (bid & 7) * (nwg >> 3) + (bid >> 3);
  int wx = swz % gridDim.x, wy = swz / gridDim.x;
  const int m0 = wy * 128;
  const int n0 = wx * 128;

  const int t = threadIdx.x;
  const int lane = t & 63, w = t >> 6;
  const int wm = w >> 1, wn = w & 1;
  const int ar = t >> 1, ah = t & 1;    // staging: row, k-half

  f32x4 acc[4][4];
  #pragma unroll
  for (int i = 0; i < 4; ++i)
    #pragma unroll
    for (int j = 0; j < 4; ++j)
      acc[i][j] = (f32x4){0.f, 0.f, 0.f, 0.f};

  uint4 aH[2], aL[2], bH[2], bL[2];
  auto gload = [&](int k0) {
    size_t aoff = (size_t)(m0 + ar) * K + k0 + ah * 16;
    aH[0] = *(const uint4*)(Ahi + aoff); aH[1] = *(const uint4*)(Ahi + aoff + 8);
    aL[0] = *(const uint4*)(Alo + aoff); aL[1] = *(const uint4*)(Alo + aoff + 8);
    size_t boff = (size_t)(n0 + ar) * K + k0 + ah * 16;
    bH[0] = *(const uint4*)(Bhi + boff); bH[1] = *(const uint4*)(Bhi + boff + 8);
    bL[0] = *(const uint4*)(Blo + boff); bL[1] = *(const uint4*)(Blo + boff + 8);
  };
  gload(0);

  const int kg = (lane >> 4) * 8;
  const int mr = lane & 15;

  for (int k0 = 0; k0 < K; k0 += 32) {
    __syncthreads();
    *(uint4*)&AHs[ar][ah * 16]     = aH[0];
    *(uint4*)&AHs[ar][ah * 16 + 8] = aH[1];
    *(uint4*)&ALs[ar][ah * 16]     = aL[0];
    *(uint4*)&ALs[ar][ah * 16 + 8] = aL[1];
    *(uint4*)&BHs[ar][ah * 16]     = bH[0];
    *(uint4*)&BHs[ar][ah * 16 + 8] = bH[1];
    *(uint4*)&BLs[ar][ah * 16]     = bL[0];
    *(uint4*)&BLs[ar][ah * 16 + 8] = bL[1];
    __syncthreads();
    if (k0 + 32 < K) gload(k0 + 32);

    bf16x8 afH[4], afL[4], bfH[4], bfL[4];
    #pragma unroll
    for (int i = 0; i < 4; ++i) {
      afH[i] = *(const bf16x8*)&AHs[wm * 64 + i * 16 + mr][kg];
      afL[i] = *(const bf16x8*)&ALs[wm * 64 + i * 16 + mr][kg];
    }
    #pragma unroll
    for (int j = 0; j < 4; ++j) {
      bfH[j] = *(const bf16x8*)&BHs[wn * 64 + j * 16 + mr][kg];
      bfL[j] = *(const bf16x8*)&BLs[wn * 64 + j * 16 + mr][kg];
    }
    #pragma unroll
    for (int i = 0; i < 4; ++i)
      #pragma unroll
      for (int j = 0; j < 4; ++j) {
        acc[i][j] = __builtin_amdgcn_mfma_f32_16x16x32_bf16(afH[i], bfH[j], acc[i][j], 0, 0, 0);
        acc[i][j] = __builtin_amdgcn_mfma_f32_16x16x32_bf16(afH[i], bfL[j], acc[i][j], 0, 0, 0);
        acc[i][j] = __builtin_amdgcn_mfma_f32_16x16x32_bf16(afL[i], bfH[j], acc[i][j], 0, 0, 0);
      }
  }

  const int lr4 = (lane >> 4) * 4;
  const int lc = lane & 15;
  #pragma unroll
  for (int i = 0; i < 4; ++i)
    #pragma unroll
    for (int r = 0; r < 4; ++r) {
      int row = m0 + wm * 64 + i * 16 + lr4 + r;
      size_t crow = (size_t)row * N;
      #pragma unroll
      for (int j = 0; j < 4; ++j) {
        int col = n0 + wn * 64 + j * 16 + lc;
        float v = acc[i][j][r] + biasp[col];
        if (RES) v += Rp[crow + col];
        if (SPLITOUT) {
          unsigned short hi = f2bf(v);
          Chi[crow + col] = hi;
          Clo[crow + col] = f2bf(v - bf2f(hi));
        } else {
          Cf[crow + col] = v;
        }
      }
    }
}

// ---------------- MoE bf16 MFMA GEMM (unchanged, verified r11) ---------------
template <int GATHER, int RELU, int K, int N>
__global__ __launch_bounds__(256) void moe_mfma_kernel(
    const unsigned short* __restrict__ Abf, const unsigned short* __restrict__ Bbf,
    unsigned short* __restrict__ Cbf,
    const int* __restrict__ gatherp, const int* __restrict__ cntp,
    const int* __restrict__ basep) {
  __shared__ unsigned short As[128][40];
  __shared__ unsigned short Bs[128][40];

  const int e = blockIdx.z;
  const int M = cntp[e];
  const int rowOff = basep[e];
  if ((int)blockIdx.y * 128 >= M) return;
  const unsigned short* Bg = Bbf + (size_t)e * K * N;
  const int m0 = blockIdx.y * 128;
  const int n0 = blockIdx.x * 128;
  const int t = threadIdx.x;
  const int lane = t & 63, w = t >> 6;
  const int wm = w >> 1, wn = w & 1;

  const int ar = t >> 1, ah = t & 1;
  size_t abase;
  {
    int r = m0 + ar;
    int mm = M - 1; r = r < mm ? r : mm;
    if (GATHER) r = gatherp[rowOff + r];
    else        r += rowOff;
    abase = (size_t)r * K;
  }
  const int bk = t >> 3, bn = (t & 7) * 16;

  f32x4 acc[4][4];
  #pragma unroll
  for (int i = 0; i < 4; ++i)
    #pragma unroll
    for (int j = 0; j < 4; ++j)
      acc[i][j] = (f32x4){0.f, 0.f, 0.f, 0.f};

  uint4 aR0, aR1, bR0, bR1;
  auto gload = [&](int k0) {
    aR0 = *(const uint4*)(Abf + abase + k0 + ah * 16);
    aR1 = *(const uint4*)(Abf + abase + k0 + ah * 16 + 8);
    bR0 = *(const uint4*)(Bg + (size_t)(k0 + bk) * N + n0 + bn);
    bR1 = *(const uint4*)(Bg + (size_t)(k0 + bk) * N + n0 + bn + 8);
  };
  gload(0);

  const int kg = (lane >> 4) * 8;
  const int mr = lane & 15;

  for (int k0 = 0; k0 < K; k0 += 32) {
    __syncthreads();
    *(uint4*)&As[ar][ah * 16]     = aR0;
    *(uint4*)&As[ar][ah * 16 + 8] = aR1;
    {
      unsigned short tmp[16];
      *(uint4*)tmp       = bR0;
      *(uint4*)(tmp + 8) = bR1;
      #pragma unroll
      for (int j = 0; j < 16; ++j) Bs[bn + j][bk] = tmp[j];
    }
    __syncthreads();
    if (k0 + 32 < K) gload(k0 + 32);

    bf16x8 af[4], bfr[4];
    #pragma unroll
    for (int i = 0; i < 4; ++i)
      af[i] = *(const bf16x8*)&As[wm * 64 + i * 16 + mr][kg];
    #pragma unroll
    for (int j = 0; j < 4; ++j)
      bfr[j] = *(const bf16x8*)&Bs[wn * 64 + j * 16 + mr][kg];
    #pragma unroll
    for (int i = 0; i < 4; ++i)
      #pragma unroll
      for (int j = 0; j < 4; ++j)
        acc[i][j] = __builtin_amdgcn_mfma_f32_16x16x32_bf16(
            af[i], bfr[j], acc[i][j], 0, 0, 0);
  }

  const int lr4 = (lane >> 4) * 4;
  const int lc = lane & 15;
  #pragma unroll
  for (int i = 0; i < 4; ++i)
    #pragma unroll
    for (int r = 0; r < 4; ++r) {
      int row = m0 + wm * 64 + i * 16 + lr4 + r;
      if (row >= M) continue;
      size_t crow = (size_t)(row + rowOff) * N;
      #pragma unroll
      for (int j = 0; j < 4; ++j) {
        float v = acc[i][j][r];
        if (RELU) v = v > 0.f ? v : 0.f;
        Cbf[crow + n0 + wn * 64 + j * 16 + lc] = f2bf(v);
      }
    }
}

// ---------------- Flash attention: split-bf16 MFMA, pre-split I/O ------------
DI int pswz(int row) { return ((row >> 1) & 7) << 3; }

__global__ __launch_bounds__(256) void flash_kernel(
    const unsigned short* __restrict__ qh, const unsigned short* __restrict__ ql,
    unsigned short* __restrict__ aohi, unsigned short* __restrict__ aolo) {
  __shared__ unsigned short KPhi[64][72];   // K during QK; P during PV
  __shared__ unsigned short KPlo[64][72];
  __shared__ unsigned short Vthi[64][72];   // V^T: [d][kv]
  __shared__ unsigned short Vtlo[64][72];

  int bid = blockIdx.y * 32 + blockIdx.x;   // grid (32, 32)
  int swzb = (bid & 7) * 128 + (bid >> 3);
  const int bh = swzb >> 5;
  const int qt = swzb & 31;
  const int b = bh >> 3, h = bh & 7;
  const int t = threadIdx.x;
  const int w = t >> 6, lane = t & 63;
  const int l15 = lane & 15, l4 = lane >> 4;
  const int lr = t >> 2;
  const int dbase = (t & 3) * 16;
  const int vd = t & 63;
  const int kv0 = (t >> 6) * 16;

  bf16x8 qhi[2], qlo[2];
  {
    int qglob = qt * 64 + w * 16 + l15;
    size_t qoff = ((size_t)(qglob * kB + b)) * (3 * kE) + h * kHD;
    #pragma unroll
    for (int ks = 0; ks < 2; ++ks) {
      qhi[ks] = *(const bf16x8*)(qh + qoff + ks * 32 + l4 * 8);
      qlo[ks] = *(const bf16x8*)(ql + qoff + ks * 32 + l4 * 8);
    }
  }

  float m_i[4], l_i[4];
  f32x4 Oacc[4];
  #pragma unroll
  for (int r = 0; r < 4; ++r) { m_i[r] = -1e30f; l_i[r] = 0.f; }
  #pragma unroll
  for (int df = 0; df < 4; ++df) Oacc[df] = (f32x4){0.f, 0.f, 0.f, 0.f};

  uint4 kh[2], kl[2];
  unsigned short vh[16], vl[16];
  auto kv_load = [&](int ktile) {
    size_t koff = ((size_t)((ktile * 64 + lr) * kB + b)) * (3 * kE) + kE + h * kHD + dbase;
    kh[0] = *(const uint4*)(qh + koff);
    kh[1] = *(const uint4*)(qh + koff + 8);
    kl[0] = *(const uint4*)(ql + koff);
    kl[1] = *(const uint4*)(ql + koff + 8);
    #pragma unroll
    for (int j = 0; j < 16; ++j) {
      size_t voff = ((size_t)((ktile * 64 + kv0 + j) * kB + b)) * (3 * kE) + 2 * kE + h * kHD + vd;
      vh[j] = qh[voff];
      vl[j] = ql[voff];
    }
  };
  kv_load(0);

  for (int kt = 0; kt < 32; ++kt) {
    __syncthreads();
    {
      int sw = pswz(lr);
      *(uint4*)&KPhi[lr][(dbase)     ^ sw] = kh[0];
      *(uint4*)&KPhi[lr][(dbase + 8) ^ sw] = kh[1];
      *(uint4*)&KPlo[lr][(dbase)     ^ sw] = kl[0];
      *(uint4*)&KPlo[lr][(dbase + 8) ^ sw] = kl[1];
      int swv = pswz(vd);
      *(uint4*)&Vthi[vd][(kv0)     ^ swv] = ((uint4*)vh)[0];
      *(uint4*)&Vthi[vd][(kv0 + 8) ^ swv] = ((uint4*)vh)[1];
      *(uint4*)&Vtlo[vd][(kv0)     ^ swv] = ((uint4*)vl)[0];
      *(uint4*)&Vtlo[vd][(kv0 + 8) ^ swv] = ((uint4*)vl)[1];
    }
    __syncthreads();
    if (kt + 1 < 32) kv_load(kt + 1);

    f32x4 acc[4];
    #pragma unroll
    for (int nf = 0; nf < 4; ++nf) acc[nf] = (f32x4){0.f, 0.f, 0.f, 0.f};
    #pragma unroll
    for (int ks = 0; ks < 2; ++ks) {
      #pragma unroll
      for (int nf = 0; nf < 4; ++nf) {
        int krow = nf * 16 + l15;
        int off = (ks * 32 + l4 * 8) ^ pswz(krow);
        bf16x8 kkh = *(const bf16x8*)&KPhi[krow][off];
        bf16x8 kkl = *(const bf16x8*)&KPlo[krow][off];
        acc[nf] = __builtin_amdgcn_mfma_f32_16x16x32_bf16(qhi[ks], kkh, acc[nf], 0, 0, 0);
        acc[nf] = __builtin_amdgcn_mfma_f32_16x16x32_bf16(qhi[ks], kkl, acc[nf], 0, 0, 0);
        acc[nf] = __builtin_amdgcn_mfma_f32_16x16x32_bf16(qlo[ks], kkh, acc[nf], 0, 0, 0);
      }
    }
    #pragma unroll
    for (int nf = 0; nf < 4; ++nf)
      #pragma unroll
      for (int r = 0; r < 4; ++r) acc[nf][r] *= 0.125f;

    float pv[4][4];
    float alpha[4];
    #pragma unroll
    for (int r = 0; r < 4; ++r) {
      float tm = fmaxf(fmaxf(acc[0][r], acc[1][r]), fmaxf(acc[2][r], acc[3][r]));
      #pragma unroll
      for (int m = 1; m < 16; m <<= 1) tm = fmaxf(tm, __shfl_xor(tm, m));
      float mn = fmaxf(m_i[r], tm);
      alpha[r] = __expf(m_i[r] - mn);
      m_i[r] = mn;
      float rs = 0.f;
      #pragma unroll
      for (int nf = 0; nf < 4; ++nf) {
        float p = __expf(acc[nf][r] - mn);
        pv[r][nf] = p;
        rs += p;
      }
      #pragma unroll
      for (int m = 1; m < 16; m <<= 1) rs += __shfl_xor(rs, m);
      l_i[r] = l_i[r] * alpha[r] + rs;
    }
    #pragma unroll
    for (int df = 0; df < 4; ++df)
      #pragma unroll
      for (int r = 0; r < 4; ++r) Oacc[df][r] *= alpha[r];

    __syncthreads();
    #pragma unroll
    for (int r = 0; r < 4; ++r) {
      int qrow = w * 16 + l4 * 4 + r;
      int sw = pswz(qrow);
      #pragma unroll
      for (int nf = 0; nf < 4; ++nf) {
        int scol = (nf * 16 + l15) ^ sw;
        float p = pv[r][nf];
        unsigned short hi = f2bf(p);
        KPhi[qrow][scol] = hi;
        KPlo[qrow][scol] = f2bf(p - bf2f(hi));
      }
    }
    __syncthreads();

    {
      int prow = w * 16 + l15;
      int swp = pswz(prow);
      #pragma unroll
      for (int ks = 0; ks < 2; ++ks) {
        int koff = ks * 32 + l4 * 8;
        bf16x8 ph = *(const bf16x8*)&KPhi[prow][koff ^ swp];
        bf16x8 pl = *(const bf16x8*)&KPlo[prow][koff ^ swp];
        #pragma unroll
        for (int df = 0; df < 4; ++df) {
          int vrow = df * 16 + l15;
          int off = koff ^ pswz(vrow);
          bf16x8 vvh = *(const bf16x8*)&Vthi[vrow][off];
          bf16x8 vvl = *(const bf16x8*)&Vtlo[vrow][off];
          Oacc[df] = __builtin_amdgcn_mfma_f32_16x16x32_bf16(ph, vvh, Oacc[df], 0, 0, 0);
          Oacc[df] = __builtin_amdgcn_mfma_f32_16x16x32_bf16(ph, vvl, Oacc[df], 0, 0, 0);
          Oacc[df] = __builtin_amdgcn_mfma_f32_16x16x32_bf16(pl, vvh, Oacc[df], 0, 0, 0);
        }
      }
    }
  }

  // output: pre-split hi/lo for the out-proj MFMA
  #pragma unroll
  for (int r = 0; r < 4; ++r) {
    float inv = 1.0f / l_i[r];
    int l = qt * 64 + w * 16 + l4 * 4 + r;
    size_t obase = ((size_t)(l * kB + b)) * kE + h * kHD;
    #pragma unroll
    for (int df = 0; df < 4; ++df) {
      float o = Oacc[df][r] * inv;
      unsigned short hi = f2bf(o);
      aohi[obase + df * 16 + l15] = hi;
      aolo[obase + df * 16 + l15] = f2bf(o - bf2f(hi));
    }
  }
}

// ---------------- Gating: logits, softmax, top2, partitionable-XOR threefry --
__global__ __launch_bounds__(256) void gating_kernel(
    const float* __restrict__ h2, const float* __restrict__ wg,
    int* __restrict__ e1, int* __restrict__ e2,
    float* __restrict__ g1, float* __restrict__ g2,
    int* __restrict__ keepr) {
  __shared__ float swg[kE * kNE];
  for (int i = threadIdx.x; i < kE * kNE; i += 256) swg[i] = wg[i];
  __syncthreads();
  int w = threadIdx.x >> 6, lane = threadIdx.x & 63;
  int tok = blockIdx.x * 4 + w;
  const float* xr = h2 + (size_t)tok * kE;
  float a0=0,a1=0,a2=0,a3=0,a4=0;
  for (int d = lane; d < kE; d += 64) {
    float xv = xr[d];
    a0 = fmaf(xv, swg[d*5+0], a0);
    a1 = fmaf(xv, swg[d*5+1], a1);
    a2 = fmaf(xv, swg[d*5+2], a2);
    a3 = fmaf(xv, swg[d*5+3], a3);
    a4 = fmaf(xv, swg[d*5+4], a4);
  }
  #pragma unroll
  for (int m = 32; m; m >>= 1) {
    a0 += __shfl_xor(a0, m); a1 += __shfl_xor(a1, m); a2 += __shfl_xor(a2, m);
    a3 += __shfl_xor(a3, m); a4 += __shfl_xor(a4, m);
  }
  if (lane == 0) {
    float lg[5] = {a0, a1, a2, a3, a4};
    float mx = lg[0];
    #pragma unroll
    for (int e = 1; e < 5; ++e) mx = fmaxf(mx, lg[e]);
    float ex[5], ssum = 0.f;
    #pragma unroll
    for (int e = 0; e < 5; ++e) { ex[e] = expf(lg[e] - mx); ssum += ex[e]; }
    float raw[5];
    #pragma unroll
    for (int e = 0; e < 5; ++e) raw[e] = ex[e] / ssum;
    int i1 = 0; float v1 = raw[0];
    #pragma unroll
    for (int e = 1; e < 5; ++e) if (raw[e] > v1) { v1 = raw[e]; i1 = e; }
    int i2 = 0; float v2 = -1.f;
    #pragma unroll
    for (int e = 0; e < 5; ++e) if (e != i1 && raw[e] > v2) { v2 = raw[e]; i2 = e; }
    float denom = v1 + v2 + 1e-9f;
    float G1 = v1 / denom, G2 = v2 / denom;
    unsigned x0 = 0u, x1 = (unsigned)tok;
    threefry(x0, x1);
    unsigned bits = x0 ^ x1;
    float u = __uint_as_float((bits >> 9) | 0x3F800000u) - 1.0f;
    int kr = (u < G2 / 0.2f) ? 1 : 0;
    e1[tok] = i1; e2[tok] = i2; g1[tok] = G1; g2[tok] = G2; keepr[tok] = kr;
  }
}

// ---------------- Per-group plan: positions + capacity -----------------------
__global__ __launch_bounds__(256) void plan_kernel(
    const int* __restrict__ e1, const int* __restrict__ e2,
    const int* __restrict__ keepr,
    int* __restrict__ slot1, int* __restrict__ slot2, int* __restrict__ tot) {
  int l = blockIdx.x * blockDim.x + threadIdx.x;
  if (l >= kL) return;
  int base = l * 4;
  int e1v[4], e2v[4], kr[4];
  #pragma unroll
  for (int n = 0; n < 4; ++n) {
    e1v[n] = e1[base + n]; e2v[n] = e2[base + n]; kr[n] = keepr[base + n];
  }
  int c1[5] = {0,0,0,0,0};
  int s1[4];
  #pragma unroll
  for (int n = 0; n < 4; ++n) {
    int e = e1v[n];
    int p = 0;
    #pragma unroll
    for (int q = 0; q < 5; ++q) if (q == e) p = c1[q];
    s1[n] = p;
    #pragma unroll
    for (int q = 0; q < 5; ++q) c1[q] += (q == e);
  }
  int run[5] = {0,0,0,0,0};
  int s2[4];
  #pragma unroll
  for (int n = 0; n < 4; ++n) {
    s2[n] = -1;
    if (kr[n]) {
      int e = e2v[n];
      int p = 0;
      #pragma unroll
      for (int q = 0; q < 5; ++q) if (q == e) p = c1[q] + run[q];
      if (p < kCAP) s2[n] = p;
      #pragma unroll
      for (int q = 0; q < 5; ++q) run[q] += (q == e);
    }
  }
  #pragma unroll
  for (int n = 0; n < 4; ++n) { slot1[base + n] = s1[n]; slot2[base + n] = s2[n]; }
  int adm[5] = {0,0,0,0,0};
  #pragma unroll
  for (int n = 0; n < 4; ++n)
    if (s2[n] >= 0) {
      #pragma unroll
      for (int q = 0; q < 5; ++q) adm[q] += (q == e2v[n]);
    }
  #pragma unroll
  for (int q = 0; q < 5; ++q) tot[l * kNE + q] = c1[q] + adm[q];
}

// ---------------- Per-expert exclusive scan of group totals ------------------
__global__ __launch_bounds__(256) void scan_kernel(
    const int* __restrict__ tot, int* __restrict__ gbase, int* __restrict__ cnt) {
  int e = blockIdx.x;
  int t = threadIdx.x;
  int lane = t & 63, w = t >> 6;
  __shared__ int wsum[4];
  __shared__ int carry;
  if (t == 0) carry = 0;
  __syncthreads();
  for (int chunk = 0; chunk < kL / 256; ++chunk) {
    int g = chunk * 256 + t;
    int v = tot[g * kNE + e];
    int inc = v;
    #pragma unroll
    for (int off = 1; off < 64; off <<= 1) {
      int u = __shfl_up(inc, off);
      if (lane >= off) inc += u;
    }
    if (lane == 63) wsum[w] = inc;
    __syncthreads();
    int wb = 0;
    #pragma unroll
    for (int i = 0; i < 4; ++i) wb += (i < w) ? wsum[i] : 0;
    int total = wsum[0] + wsum[1] + wsum[2] + wsum[3];
    gbase[g * kNE + e] = carry + wb + inc - v;
    __syncthreads();
    if (t == 0) carry += total;
    __syncthreads();
  }
  if (t == 0) cnt[e] = carry;
}

__global__ void bases_kernel(const int* __restrict__ cnt, int* __restrict__ base) {
  if (threadIdx.x == 0 && blockIdx.x == 0) {
    int a = 0;
    #pragma unroll
    for (int e = 0; e < kNE; ++e) { base[e] = a; a += cnt[e]; }
  }
}

// ---------------- Row map: token -> expert-buffer rows -----------------------
__global__ __launch_bounds__(256) void rowmap_kernel(
    const int* __restrict__ e1, const int* __restrict__ e2,
    const int* __restrict__ slot1, const int* __restrict__ slot2,
    const int* __restrict__ gbase, const int* __restrict__ ebase,
    int* __restrict__ rowOf1, int* __restrict__ rowOf2,
    int* __restrict__ tokOfRow) {
  int tok = blockIdx.x * blockDim.x + threadIdx.x;
  if (tok >= kT) return;
  int l = tok >> 2;
  int a = e1[tok];
  int r1 = ebase[a] + gbase[l * kNE + a] + slot1[tok];
  rowOf1[tok] = r1;
  tokOfRow[r1] = tok;
  int s2 = slot2[tok];
  int r2 = -1;
  if (s2 >= 0) {
    int bq = e2[tok];
    r2 = ebase[bq] + gbase[l * kNE + bq] + s2;
    tokOfRow[r2] = tok;
  }
  rowOf2[tok] = r2;
}

// ---------------- Final combine: out = x_res + g1*eo[r1] + g2*eo[r2] ---------
__global__ __launch_bounds__(128) void combine_kernel(
    const float* __restrict__ xres, const unsigned short* __restrict__ eo,
    const float* __restrict__ g1, const float* __restrict__ g2,
    const int* __restrict__ rowOf1, const int* __restrict__ rowOf2,
    float* __restrict__ out) {
  int tok = blockIdx.x;
  int t = threadIdx.x;
  float4 o = *(const float4*)(xres + (size_t)tok * kE + t * 4);
  int p1 = rowOf1[tok];
  float G1 = g1[tok];
  ushort4 a = *(const ushort4*)(eo + (size_t)p1 * kE + t * 4);
  o.x += G1 * bf2f(a.x); o.y += G1 * bf2f(a.y);
  o.z += G1 * bf2f(a.z); o.w += G1 * bf2f(a.w);
  int p2 = rowOf2[tok];
  if (p2 >= 0) {
    float G2 = g2[tok];
    ushort4 c = *(const ushort4*)(eo + (size_t)p2 * kE + t * 4);
    o.x += G2 * bf2f(c.x); o.y += G2 * bf2f(c.y);
    o.z += G2 * bf2f(c.z); o.w += G2 * bf2f(c.w);
  }
  *(float4*)(out + (size_t)tok * kE + t * 4) = o;
}

}  // namespace

extern "C" void kernel_launch(void* const* d_in, const int* in_sizes, int n_in,
                              void* d_out, int out_size, void* d_ws, size_t ws_size,
                              hipStream_t stream) {
  (void)in_sizes; (void)n_in; (void)out_size;
  const float* x    = (const float*)d_in[0];
  const float* ln1w = (const float*)d_in[1];
  const float* ln1b = (const float*)d_in[2];
  const float* ln2w = (const float*)d_in[3];
  const float* ln2b = (const float*)d_in[4];
  const float* wqkv = (const float*)d_in[5];
  const float* bqkv = (const float*)d_in[6];
  const float* wo   = (const float*)d_in[7];
  const float* bo   = (const float*)d_in[8];
  const float* wg   = (const float*)d_in[9];
  const float* w1   = (const float*)d_in[10];
  const float* w2   = (const float*)d_in[11];
  float* out = (float*)d_out;

  // ws layout (float units, 33.75M total = 135 MB):
  // fixed:   xres[0,4194304) w1bf[4194304,6815744) w2bf[6815744,9437184)
  //          wqkvhi[9437184,9830400) wqkvlo[9830400,10223616)
  //          wohi[10223616,10354688) wolo[10354688,10485760)
  //          ints[10485760,10616832)
  // phase A: h1hi[10616832,12713984) h1lo[12713984,14811136)
  //          qkvhi[14811136,21102592) qkvlo[21102592,27394048)
  //          aohi[27394048,29491200) aolo[29491200,31588352)
  // phase B (reuses phase A; all phase-A buffers dead by then):
  //          h2 f32 [10616832,14811136)  -> reused as eobf after gating/h2bf
  //          h2bf [14811136,16908288)
  //          hmoe [16908288,33685504)    (16384 x 2048 bf16 = 16.78M floats)
  if (ws_size < (size_t)134742016) return;
  float* ws   = (float*)d_ws;
  float* xres = ws;
  unsigned short* w1bf   = (unsigned short*)(ws + 4194304);
  unsigned short* w2bf   = (unsigned short*)(ws + 6815744);
  unsigned short* wqkvhi = (unsigned short*)(ws + 9437184);
  unsigned short* wqkvlo = (unsigned short*)(ws + 9830400);
  unsigned short* wohi   = (unsigned short*)(ws + 10223616);
  unsigned short* wolo   = (unsigned short*)(ws + 10354688);
  int* ibuf = (int*)(ws + 10485760);
  unsigned short* h1hi  = (unsigned short*)(ws + 10616832);
  unsigned short* h1lo  = (unsigned short*)(ws + 12713984);
  unsigned short* qkvhi = (unsigned short*)(ws + 14811136);
  unsigned short* qkvlo = (unsigned short*)(ws + 21102592);
  unsigned short* aohi  = (unsigned short*)(ws + 27394048);
  unsigned short* aolo  = (unsigned short*)(ws + 29491200);
  float* h2             = ws + 10616832;
  unsigned short* eobf  = (unsigned short*)(ws + 10616832);  // reuses dead h2
  unsigned short* h2bf  = (unsigned short*)(ws + 14811136);
  unsigned short* hmoe  = (unsigned short*)(ws + 16908288);  // full 16.78M floats

  int* e1      = ibuf;
  int* e2      = e1 + kT;
  float* g1f   = (float*)(e2 + kT);
  float* g2f   = g1f + kT;
  int* keepr   = (int*)(g2f + kT);
  int* slot1   = keepr + kT;
  int* slot2   = slot1 + kT;
  int* rowOf1  = slot2 + kT;
  int* rowOf2  = rowOf1 + kT;
  int* tot     = rowOf2 + kT;
  int* gbase   = tot + kL * kNE;
  int* tokOfRow= gbase + kL * kNE;
  int* cnt     = tokOfRow + 2 * kT;
  int* ebase   = cnt + 8;

  // 0. weight conversions
  f2bf_kernel<<<5120, 256, 0, stream>>>(w1, w1bf, kNE * kE * kFF / 4);
  f2bf_kernel<<<5120, 256, 0, stream>>>(w2, w2bf, kNE * kFF * kE / 4);
  wsplit_kernel<<<768, 256, 0, stream>>>(wqkv, wqkvhi, wqkvlo, 1536 * kE / 4);
  wsplit_kernel<<<256, 256, 0, stream>>>(wo, wohi, wolo, kE * kE / 4);
  // 1. h1 = LN1(x) -> split hi/lo
  ln_kernel<1><<<kT, 256, 0, stream>>>(x, ln1w, ln1b, nullptr, h1hi, h1lo);
  // 2. qkv = h1 @ Wqkv^T + b  (split-bf16 MFMA) -> split hi/lo
  dsgemm_kernel<0,1><<<dim3(12, 64), 256, 0, stream>>>(
      h1hi, h1lo, wqkvhi, wqkvlo, bqkv, nullptr,
      nullptr, qkvhi, qkvlo, kT, 1536, kE);
  // 3. attention -> split attn_out
  flash_kernel<<<dim3(32, 32, 1), 256, 0, stream>>>(qkvhi, qkvlo, aohi, aolo);
  // 4. x_res = x + attn_out @ Wo^T + bo  (split-bf16 MFMA)
  dsgemm_kernel<1,0><<<dim3(4, 64), 256, 0, stream>>>(
      aohi, aolo, wohi, wolo, bo, x,
      xres, nullptr, nullptr, kT, kE, kE);
  // 5. h2 = LN2(x_res), f32
  ln_kernel<0><<<kT, 256, 0, stream>>>(xres, ln2w, ln2b, h2, nullptr, nullptr);
  // 6. gating per token
  gating_kernel<<<kL, 256, 0, stream>>>(h2, wg, e1, e2, g1f, g2f, keepr);
  // 6b. h2 -> bf16 (h2 f32 dead after this; slot becomes eobf)
  f2bf_kernel<<<4096, 256, 0, stream>>>(h2, h2bf, kT * kE / 4);
  // 7. per-group plan
  plan_kernel<<<kL / 256, 256, 0, stream>>>(e1, e2, keepr, slot1, slot2, tot);
  // 8. per-expert scan; bases; row maps
  scan_kernel<<<kNE, 256, 0, stream>>>(tot, gbase, cnt);
  bases_kernel<<<1, 32, 0, stream>>>(cnt, ebase);
  rowmap_kernel<<<kT / 256, 256, 0, stream>>>(
      e1, e2, slot1, slot2, gbase, ebase, rowOf1, rowOf2, tokOfRow);
  // 9. hmoe = relu(gather(h2bf) @ w1bf[e])
  moe_mfma_kernel<1,1,kE,kFF><<<dim3(16, 64, kNE), 256, 0, stream>>>(
      h2bf, w1bf, hmoe, tokOfRow, cnt, ebase);
  // 10. eo = hmoe @ w2bf[e]
  moe_mfma_kernel<0,0,kFF,kE><<<dim3(4, 64, kNE), 256, 0, stream>>>(
      hmoe, w2bf, eobf, nullptr, cnt, ebase);
  // 11. out = x_res + g1*eo + g2*eo
  combine_kernel<<<kT, 128, 0, stream>>>(
      xres, eobf, g1f, g2f, rowOf1, rowOf2, out);
}

// Round 18
// 614.353 us; speedup vs baseline: 1.2407x; 1.1708x over previous
//
#include <hip/hip_runtime.h>

#define DI __device__ __forceinline__

namespace {

constexpr int kL  = 2048;
constexpr int kB  = 4;
constexpr int kE  = 512;
constexpr int kHD = 64;
constexpr int kFF = 2048;
constexpr int kNE = 5;
constexpr int kT  = 8192;   // kL * kB tokens
constexpr int kCAP = 4;

using bf16x8 = __attribute__((ext_vector_type(8))) short;
using f32x4  = __attribute__((ext_vector_type(4))) float;

DI float bf2f(unsigned short u) { return __uint_as_float(((unsigned)u) << 16); }
DI unsigned short f2bf(float f) {
  unsigned u = __float_as_uint(f);
  u = u + 0x7FFFu + ((u >> 16) & 1u);
  return (unsigned short)(u >> 16);
}

DI unsigned rotl(unsigned v, int d) { return (v << d) | (v >> (32 - d)); }

// JAX threefry2x32 with key = PRNGKey(42) = (0, 42), 20 rounds.
DI void threefry(unsigned& x0, unsigned& x1) {
  const unsigned K1 = 0u, K2 = 42u, K3 = 0x1BD11BDAu ^ 0u ^ 42u;
  x0 += K1; x1 += K2;
  x0 += x1; x1 = rotl(x1, 13); x1 ^= x0;
  x0 += x1; x1 = rotl(x1, 15); x1 ^= x0;
  x0 += x1; x1 = rotl(x1, 26); x1 ^= x0;
  x0 += x1; x1 = rotl(x1,  6); x1 ^= x0;
  x0 += K2; x1 += K3 + 1u;
  x0 += x1; x1 = rotl(x1, 17); x1 ^= x0;
  x0 += x1; x1 = rotl(x1, 29); x1 ^= x0;
  x0 += x1; x1 = rotl(x1, 16); x1 ^= x0;
  x0 += x1; x1 = rotl(x1, 24); x1 ^= x0;
  x0 += K3; x1 += K1 + 2u;
  x0 += x1; x1 = rotl(x1, 13); x1 ^= x0;
  x0 += x1; x1 = rotl(x1, 15); x1 ^= x0;
  x0 += x1; x1 = rotl(x1, 26); x1 ^= x0;
  x0 += x1; x1 = rotl(x1,  6); x1 ^= x0;
  x0 += K1; x1 += K2 + 3u;
  x0 += x1; x1 = rotl(x1, 17); x1 ^= x0;
  x0 += x1; x1 = rotl(x1, 29); x1 ^= x0;
  x0 += x1; x1 = rotl(x1, 16); x1 ^= x0;
  x0 += x1; x1 = rotl(x1, 24); x1 ^= x0;
  x0 += K2; x1 += K3 + 4u;
  x0 += x1; x1 = rotl(x1, 13); x1 ^= x0;
  x0 += x1; x1 = rotl(x1, 15); x1 ^= x0;
  x0 += x1; x1 = rotl(x1, 26); x1 ^= x0;
  x0 += x1; x1 = rotl(x1,  6); x1 ^= x0;
  x0 += K3; x1 += K1 + 5u;
}

// ---------------- f32 [z][R][C] -> bf16 [z][C][R] tiled transpose ------------
__global__ __launch_bounds__(256) void tsplit_kernel(
    const float* __restrict__ in, unsigned short* __restrict__ outbf,
    int R, int C) {
  __shared__ unsigned short tile[64][72];
  int z = blockIdx.z;
  int c0 = blockIdx.x * 64, r0 = blockIdx.y * 64;
  int t = threadIdx.x;
  int rr = t >> 2, cb = (t & 3) * 16;
  const float* src = in + ((size_t)z * R + r0 + rr) * C + c0 + cb;
  #pragma unroll
  for (int j = 0; j < 4; ++j) {
    float4 v = *(const float4*)(src + 4 * j);
    tile[rr][cb + 4*j + 0] = f2bf(v.x);
    tile[rr][cb + 4*j + 1] = f2bf(v.y);
    tile[rr][cb + 4*j + 2] = f2bf(v.z);
    tile[rr][cb + 4*j + 3] = f2bf(v.w);
  }
  __syncthreads();
  int cc = t >> 2, rb = (t & 3) * 16;
  unsigned short tmp[16];
  #pragma unroll
  for (int j = 0; j < 16; ++j) tmp[j] = tile[rb + j][cc];
  unsigned short* dst = outbf + ((size_t)z * C + c0 + cc) * R + r0 + rb;
  *(uint4*)(dst)     = ((uint4*)tmp)[0];
  *(uint4*)(dst + 8) = ((uint4*)tmp)[1];
}

// ---------------- f32 -> split hi/lo bf16 bulk -------------------------------
__global__ __launch_bounds__(256) void wsplit_kernel(
    const float* __restrict__ src, unsigned short* __restrict__ hi,
    unsigned short* __restrict__ lo, int n4) {
  int i = blockIdx.x * blockDim.x + threadIdx.x;
  if (i >= n4) return;
  float4 v = ((const float4*)src)[i];
  float va[4] = {v.x, v.y, v.z, v.w};
  ushort4 h4, l4;
  unsigned short* hp = (unsigned short*)&h4;
  unsigned short* lp = (unsigned short*)&l4;
  #pragma unroll
  for (int j = 0; j < 4; ++j) {
    unsigned short h = f2bf(va[j]);
    hp[j] = h;
    lp[j] = f2bf(va[j] - bf2f(h));
  }
  ((ushort4*)hi)[i] = h4;
  ((ushort4*)lo)[i] = l4;
}

// ---------------- LayerNorm; SPLIT=1: hi/lo bf16; SPLIT=2: f32 + plain bf16 --
template <int SPLIT>
__global__ __launch_bounds__(256) void ln_kernel(
    const float* __restrict__ x, const float* __restrict__ w,
    const float* __restrict__ b, float* __restrict__ out,
    unsigned short* __restrict__ ohi, unsigned short* __restrict__ olo) {
  int row = blockIdx.x;
  const float* xr = x + (size_t)row * kE;
  int t = threadIdx.x;
  float2 v = *(const float2*)(xr + t * 2);
  __shared__ float red[4];
  float s = v.x + v.y;
  #pragma unroll
  for (int m = 32; m; m >>= 1) s += __shfl_xor(s, m);
  if ((t & 63) == 0) red[t >> 6] = s;
  __syncthreads();
  float mu = (red[0] + red[1] + red[2] + red[3]) * (1.0f / kE);
  float dx = v.x - mu, dy = v.y - mu;
  float q = dx * dx + dy * dy;
  #pragma unroll
  for (int m = 32; m; m >>= 1) q += __shfl_xor(q, m);
  __syncthreads();
  if ((t & 63) == 0) red[t >> 6] = q;
  __syncthreads();
  float var = (red[0] + red[1] + red[2] + red[3]) * (1.0f / kE);
  float inv = 1.0f / sqrtf(var + 1e-5f);
  float ox = dx * inv * w[t * 2]     + b[t * 2];
  float oy = dy * inv * w[t * 2 + 1] + b[t * 2 + 1];
  size_t base = (size_t)row * kE + t * 2;
  if (SPLIT == 1) {
    unsigned short hx = f2bf(ox), hy = f2bf(oy);
    ohi[base] = hx; ohi[base + 1] = hy;
    olo[base] = f2bf(ox - bf2f(hx)); olo[base + 1] = f2bf(oy - bf2f(hy));
  } else if (SPLIT == 2) {
    *(float2*)(out + base) = make_float2(ox, oy);
    ohi[base] = f2bf(ox); ohi[base + 1] = f2bf(oy);
  } else {
    *(float2*)(out + base) = make_float2(ox, oy);
  }
}

// ---------------- Dense split-bf16 MFMA GEMM: C = A*B^T (+bias)(+R) ----------
template <int RES, int SPLITOUT>
__global__ __launch_bounds__(256) void dsgemm_kernel(
    const unsigned short* __restrict__ Ahi, const unsigned short* __restrict__ Alo,
    const unsigned short* __restrict__ Bhi, const unsigned short* __restrict__ Blo,
    const float* __restrict__ biasp, const float* __restrict__ Rp,
    float* __restrict__ Cf, unsigned short* __restrict__ Chi,
    unsigned short* __restrict__ Clo, int M, int N, int K) {
  __shared__ unsigned short AHs[128][40];
  __shared__ unsigned short ALs[128][40];
  __shared__ unsigned short BHs[128][40];
  __shared__ unsigned short BLs[128][40];

  int nwg = gridDim.x * gridDim.y;
  int bid = blockIdx.y * gridDim.x + blockIdx.x;
  int swz = (bid & 7) * (nwg >> 3) + (bid >> 3);
  int wx = swz % gridDim.x, wy = swz / gridDim.x;
  const int m0 = wy * 128;
  const int n0 = wx * 128;

  const int t = threadIdx.x;
  const int lane = t & 63, w = t >> 6;
  const int wm = w >> 1, wn = w & 1;
  const int ar = t >> 1, ah = t & 1;    // staging: row, k-half

  f32x4 acc[4][4];
  #pragma unroll
  for (int i = 0; i < 4; ++i)
    #pragma unroll
    for (int j = 0; j < 4; ++j)
      acc[i][j] = (f32x4){0.f, 0.f, 0.f, 0.f};

  uint4 aH[2], aL[2], bH[2], bL[2];
  auto gload = [&](int k0) {
    size_t aoff = (size_t)(m0 + ar) * K + k0 + ah * 16;
    aH[0] = *(const uint4*)(Ahi + aoff); aH[1] = *(const uint4*)(Ahi + aoff + 8);
    aL[0] = *(const uint4*)(Alo + aoff); aL[1] = *(const uint4*)(Alo + aoff + 8);
    size_t boff = (size_t)(n0 + ar) * K + k0 + ah * 16;
    bH[0] = *(const uint4*)(Bhi + boff); bH[1] = *(const uint4*)(Bhi + boff + 8);
    bL[0] = *(const uint4*)(Blo + boff); bL[1] = *(const uint4*)(Blo + boff + 8);
  };
  gload(0);

  const int kg = (lane >> 4) * 8;
  const int mr = lane & 15;

  for (int k0 = 0; k0 < K; k0 += 32) {
    __syncthreads();
    *(uint4*)&AHs[ar][ah * 16]     = aH[0];
    *(uint4*)&AHs[ar][ah * 16 + 8] = aH[1];
    *(uint4*)&ALs[ar][ah * 16]     = aL[0];
    *(uint4*)&ALs[ar][ah * 16 + 8] = aL[1];
    *(uint4*)&BHs[ar][ah * 16]     = bH[0];
    *(uint4*)&BHs[ar][ah * 16 + 8] = bH[1];
    *(uint4*)&BLs[ar][ah * 16]     = bL[0];
    *(uint4*)&BLs[ar][ah * 16 + 8] = bL[1];
    __syncthreads();
    if (k0 + 32 < K) gload(k0 + 32);

    bf16x8 afH[4], afL[4], bfH[4], bfL[4];
    #pragma unroll
    for (int i = 0; i < 4; ++i) {
      afH[i] = *(const bf16x8*)&AHs[wm * 64 + i * 16 + mr][kg];
      afL[i] = *(const bf16x8*)&ALs[wm * 64 + i * 16 + mr][kg];
    }
    #pragma unroll
    for (int j = 0; j < 4; ++j) {
      bfH[j] = *(const bf16x8*)&BHs[wn * 64 + j * 16 + mr][kg];
      bfL[j] = *(const bf16x8*)&BLs[wn * 64 + j * 16 + mr][kg];
    }
    #pragma unroll
    for (int i = 0; i < 4; ++i)
      #pragma unroll
      for (int j = 0; j < 4; ++j) {
        acc[i][j] = __builtin_amdgcn_mfma_f32_16x16x32_bf16(afH[i], bfH[j], acc[i][j], 0, 0, 0);
        acc[i][j] = __builtin_amdgcn_mfma_f32_16x16x32_bf16(afH[i], bfL[j], acc[i][j], 0, 0, 0);
        acc[i][j] = __builtin_amdgcn_mfma_f32_16x16x32_bf16(afL[i], bfH[j], acc[i][j], 0, 0, 0);
      }
  }

  const int lr4 = (lane >> 4) * 4;
  const int lc = lane & 15;
  #pragma unroll
  for (int i = 0; i < 4; ++i)
    #pragma unroll
    for (int r = 0; r < 4; ++r) {
      int row = m0 + wm * 64 + i * 16 + lr4 + r;
      size_t crow = (size_t)row * N;
      #pragma unroll
      for (int j = 0; j < 4; ++j) {
        int col = n0 + wn * 64 + j * 16 + lc;
        float v = acc[i][j][r] + biasp[col];
        if (RES) v += Rp[crow + col];
        if (SPLITOUT) {
          unsigned short hi = f2bf(v);
          Chi[crow + col] = hi;
          Clo[crow + col] = f2bf(v - bf2f(hi));
        } else {
          Cf[crow + col] = v;
        }
      }
    }
}

// ---------------- MoE bf16 MFMA GEMM; B pre-transposed [E][N][K] -------------
template <int GATHER, int RELU, int K, int N>
__global__ __launch_bounds__(256) void moe_mfma_kernel(
    const unsigned short* __restrict__ Abf, const unsigned short* __restrict__ Bbf,
    unsigned short* __restrict__ Cbf,
    const int* __restrict__ gatherp, const int* __restrict__ cntp,
    const int* __restrict__ basep) {
  __shared__ unsigned short As[128][40];
  __shared__ unsigned short Bs[128][40];

  const int e = blockIdx.z;
  const int M = cntp[e];
  const int rowOff = basep[e];
  if ((int)blockIdx.y * 128 >= M) return;
  const unsigned short* Bg = Bbf + (size_t)e * K * N;
  const int m0 = blockIdx.y * 128;
  const int n0 = blockIdx.x * 128;
  const int t = threadIdx.x;
  const int lane = t & 63, w = t >> 6;
  const int wm = w >> 1, wn = w & 1;

  const int ar = t >> 1, ah = t & 1;
  size_t abase;
  {
    int r = m0 + ar;
    int mm = M - 1; r = r < mm ? r : mm;
    if (GATHER) r = gatherp[rowOff + r];
    else        r += rowOff;
    abase = (size_t)r * K;
  }
  size_t bbase = (size_t)(n0 + ar) * K;

  f32x4 acc[4][4];
  #pragma unroll
  for (int i = 0; i < 4; ++i)
    #pragma unroll
    for (int j = 0; j < 4; ++j)
      acc[i][j] = (f32x4){0.f, 0.f, 0.f, 0.f};

  uint4 aR0, aR1, bR0, bR1;
  auto gload = [&](int k0) {
    aR0 = *(const uint4*)(Abf + abase + k0 + ah * 16);
    aR1 = *(const uint4*)(Abf + abase + k0 + ah * 16 + 8);
    bR0 = *(const uint4*)(Bg + bbase + k0 + ah * 16);
    bR1 = *(const uint4*)(Bg + bbase + k0 + ah * 16 + 8);
  };
  gload(0);

  const int kg = (lane >> 4) * 8;
  const int mr = lane & 15;

  for (int k0 = 0; k0 < K; k0 += 32) {
    __syncthreads();
    *(uint4*)&As[ar][ah * 16]     = aR0;
    *(uint4*)&As[ar][ah * 16 + 8] = aR1;
    *(uint4*)&Bs[ar][ah * 16]     = bR0;
    *(uint4*)&Bs[ar][ah * 16 + 8] = bR1;
    __syncthreads();
    if (k0 + 32 < K) gload(k0 + 32);

    bf16x8 af[4], bfr[4];
    #pragma unroll
    for (int i = 0; i < 4; ++i)
      af[i] = *(const bf16x8*)&As[wm * 64 + i * 16 + mr][kg];
    #pragma unroll
    for (int j = 0; j < 4; ++j)
      bfr[j] = *(const bf16x8*)&Bs[wn * 64 + j * 16 + mr][kg];
    #pragma unroll
    for (int i = 0; i < 4; ++i)
      #pragma unroll
      for (int j = 0; j < 4; ++j)
        acc[i][j] = __builtin_amdgcn_mfma_f32_16x16x32_bf16(
            af[i], bfr[j], acc[i][j], 0, 0, 0);
  }

  const int lr4 = (lane >> 4) * 4;
  const int lc = lane & 15;
  #pragma unroll
  for (int i = 0; i < 4; ++i)
    #pragma unroll
    for (int r = 0; r < 4; ++r) {
      int row = m0 + wm * 64 + i * 16 + lr4 + r;
      if (row >= M) continue;
      size_t crow = (size_t)(row + rowOff) * N;
      #pragma unroll
      for (int j = 0; j < 4; ++j) {
        float v = acc[i][j][r];
        if (RELU) v = v > 0.f ? v : 0.f;
        Cbf[crow + n0 + wn * 64 + j * 16 + lc] = f2bf(v);
      }
    }
}

// ---------------- Flash attention: split-bf16 MFMA, pre-split I/O ------------
DI int pswz(int row) { return ((row >> 1) & 7) << 3; }

__global__ __launch_bounds__(256) void flash_kernel(
    const unsigned short* __restrict__ qh, const unsigned short* __restrict__ ql,
    unsigned short* __restrict__ aohi, unsigned short* __restrict__ aolo) {
  __shared__ unsigned short KPhi[64][72];   // K during QK; P during PV
  __shared__ unsigned short KPlo[64][72];
  __shared__ unsigned short Vthi[64][72];   // V^T: [d][kv]
  __shared__ unsigned short Vtlo[64][72];

  int bid = blockIdx.y * 32 + blockIdx.x;   // grid (32, 32)
  int swzb = (bid & 7) * 128 + (bid >> 3);
  const int bh = swzb >> 5;
  const int qt = swzb & 31;
  const int b = bh >> 3, h = bh & 7;
  const int t = threadIdx.x;
  const int w = t >> 6, lane = t & 63;
  const int l15 = lane & 15, l4 = lane >> 4;
  const int lr = t >> 2;
  const int dbase = (t & 3) * 16;
  const int vd = t & 63;
  const int kv0 = (t >> 6) * 16;

  bf16x8 qhi[2], qlo[2];
  {
    int qglob = qt * 64 + w * 16 + l15;
    size_t qoff = ((size_t)(qglob * kB + b)) * (3 * kE) + h * kHD;
    #pragma unroll
    for (int ks = 0; ks < 2; ++ks) {
      qhi[ks] = *(const bf16x8*)(qh + qoff + ks * 32 + l4 * 8);
      qlo[ks] = *(const bf16x8*)(ql + qoff + ks * 32 + l4 * 8);
    }
  }

  float m_i[4], l_i[4];
  f32x4 Oacc[4];
  #pragma unroll
  for (int r = 0; r < 4; ++r) { m_i[r] = -1e30f; l_i[r] = 0.f; }
  #pragma unroll
  for (int df = 0; df < 4; ++df) Oacc[df] = (f32x4){0.f, 0.f, 0.f, 0.f};

  uint4 kh[2], kl[2];
  unsigned short vh[16], vl[16];
  auto kv_load = [&](int ktile) {
    size_t koff = ((size_t)((ktile * 64 + lr) * kB + b)) * (3 * kE) + kE + h * kHD + dbase;
    kh[0] = *(const uint4*)(qh + koff);
    kh[1] = *(const uint4*)(qh + koff + 8);
    kl[0] = *(const uint4*)(ql + koff);
    kl[1] = *(const uint4*)(ql + koff + 8);
    #pragma unroll
    for (int j = 0; j < 16; ++j) {
      size_t voff = ((size_t)((ktile * 64 + kv0 + j) * kB + b)) * (3 * kE) + 2 * kE + h * kHD + vd;
      vh[j] = qh[voff];
      vl[j] = ql[voff];
    }
  };
  kv_load(0);

  for (int kt = 0; kt < 32; ++kt) {
    __syncthreads();
    {
      int sw = pswz(lr);
      *(uint4*)&KPhi[lr][(dbase)     ^ sw] = kh[0];
      *(uint4*)&KPhi[lr][(dbase + 8) ^ sw] = kh[1];
      *(uint4*)&KPlo[lr][(dbase)     ^ sw] = kl[0];
      *(uint4*)&KPlo[lr][(dbase + 8) ^ sw] = kl[1];
      int swv = pswz(vd);
      *(uint4*)&Vthi[vd][(kv0)     ^ swv] = ((uint4*)vh)[0];
      *(uint4*)&Vthi[vd][(kv0 + 8) ^ swv] = ((uint4*)vh)[1];
      *(uint4*)&Vtlo[vd][(kv0)     ^ swv] = ((uint4*)vl)[0];
      *(uint4*)&Vtlo[vd][(kv0 + 8) ^ swv] = ((uint4*)vl)[1];
    }
    __syncthreads();
    if (kt + 1 < 32) kv_load(kt + 1);

    f32x4 acc[4];
    #pragma unroll
    for (int nf = 0; nf < 4; ++nf) acc[nf] = (f32x4){0.f, 0.f, 0.f, 0.f};
    #pragma unroll
    for (int ks = 0; ks < 2; ++ks) {
      #pragma unroll
      for (int nf = 0; nf < 4; ++nf) {
        int krow = nf * 16 + l15;
        int off = (ks * 32 + l4 * 8) ^ pswz(krow);
        bf16x8 kkh = *(const bf16x8*)&KPhi[krow][off];
        bf16x8 kkl = *(const bf16x8*)&KPlo[krow][off];
        acc[nf] = __builtin_amdgcn_mfma_f32_16x16x32_bf16(qhi[ks], kkh, acc[nf], 0, 0, 0);
        acc[nf] = __builtin_amdgcn_mfma_f32_16x16x32_bf16(qhi[ks], kkl, acc[nf], 0, 0, 0);
        acc[nf] = __builtin_amdgcn_mfma_f32_16x16x32_bf16(qlo[ks], kkh, acc[nf], 0, 0, 0);
      }
    }
    #pragma unroll
    for (int nf = 0; nf < 4; ++nf)
      #pragma unroll
      for (int r = 0; r < 4; ++r) acc[nf][r] *= 0.125f;

    float pv[4][4];
    float alpha[4];
    #pragma unroll
    for (int r = 0; r < 4; ++r) {
      float tm = fmaxf(fmaxf(acc[0][r], acc[1][r]), fmaxf(acc[2][r], acc[3][r]));
      #pragma unroll
      for (int m = 1; m < 16; m <<= 1) tm = fmaxf(tm, __shfl_xor(tm, m));
      float mn = fmaxf(m_i[r], tm);
      alpha[r] = __expf(m_i[r] - mn);
      m_i[r] = mn;
      float rs = 0.f;
      #pragma unroll
      for (int nf = 0; nf < 4; ++nf) {
        float p = __expf(acc[nf][r] - mn);
        pv[r][nf] = p;
        rs += p;
      }
      #pragma unroll
      for (int m = 1; m < 16; m <<= 1) rs += __shfl_xor(rs, m);
      l_i[r] = l_i[r] * alpha[r] + rs;
    }
    #pragma unroll
    for (int df = 0; df < 4; ++df)
      #pragma unroll
      for (int r = 0; r < 4; ++r) Oacc[df][r] *= alpha[r];

    __syncthreads();
    #pragma unroll
    for (int r = 0; r < 4; ++r) {
      int qrow = w * 16 + l4 * 4 + r;
      int sw = pswz(qrow);
      #pragma unroll
      for (int nf = 0; nf < 4; ++nf) {
        int scol = (nf * 16 + l15) ^ sw;
        float p = pv[r][nf];
        unsigned short hi = f2bf(p);
        KPhi[qrow][scol] = hi;
        KPlo[qrow][scol] = f2bf(p - bf2f(hi));
      }
    }
    __syncthreads();

    {
      int prow = w * 16 + l15;
      int swp = pswz(prow);
      #pragma unroll
      for (int ks = 0; ks < 2; ++ks) {
        int koff = ks * 32 + l4 * 8;
        bf16x8 ph = *(const bf16x8*)&KPhi[prow][koff ^ swp];
        bf16x8 pl = *(const bf16x8*)&KPlo[prow][koff ^ swp];
        #pragma unroll
        for (int df = 0; df < 4; ++df) {
          int vrow = df * 16 + l15;
          int off = koff ^ pswz(vrow);
          bf16x8 vvh = *(const bf16x8*)&Vthi[vrow][off];
          bf16x8 vvl = *(const bf16x8*)&Vtlo[vrow][off];
          Oacc[df] = __builtin_amdgcn_mfma_f32_16x16x32_bf16(ph, vvh, Oacc[df], 0, 0, 0);
          Oacc[df] = __builtin_amdgcn_mfma_f32_16x16x32_bf16(ph, vvl, Oacc[df], 0, 0, 0);
          Oacc[df] = __builtin_amdgcn_mfma_f32_16x16x32_bf16(pl, vvh, Oacc[df], 0, 0, 0);
        }
      }
    }
  }

  // output: pre-split hi/lo for the out-proj MFMA
  #pragma unroll
  for (int r = 0; r < 4; ++r) {
    float inv = 1.0f / l_i[r];
    int l = qt * 64 + w * 16 + l4 * 4 + r;
    size_t obase = ((size_t)(l * kB + b)) * kE + h * kHD;
    #pragma unroll
    for (int df = 0; df < 4; ++df) {
      float o = Oacc[df][r] * inv;
      unsigned short hi = f2bf(o);
      aohi[obase + df * 16 + l15] = hi;
      aolo[obase + df * 16 + l15] = f2bf(o - bf2f(hi));
    }
  }
}

// ---------------- Gating: logits, softmax, top2, partitionable-XOR threefry --
__global__ __launch_bounds__(256) void gating_kernel(
    const float* __restrict__ h2, const float* __restrict__ wg,
    int* __restrict__ e1, int* __restrict__ e2,
    float* __restrict__ g1, float* __restrict__ g2,
    int* __restrict__ keepr) {
  __shared__ float swg[kE * kNE];
  for (int i = threadIdx.x; i < kE * kNE; i += 256) swg[i] = wg[i];
  __syncthreads();
  int w = threadIdx.x >> 6, lane = threadIdx.x & 63;
  int tok = blockIdx.x * 4 + w;
  const float* xr = h2 + (size_t)tok * kE;
  float a0=0,a1=0,a2=0,a3=0,a4=0;
  for (int d = lane; d < kE; d += 64) {
    float xv = xr[d];
    a0 = fmaf(xv, swg[d*5+0], a0);
    a1 = fmaf(xv, swg[d*5+1], a1);
    a2 = fmaf(xv, swg[d*5+2], a2);
    a3 = fmaf(xv, swg[d*5+3], a3);
    a4 = fmaf(xv, swg[d*5+4], a4);
  }
  #pragma unroll
  for (int m = 32; m; m >>= 1) {
    a0 += __shfl_xor(a0, m); a1 += __shfl_xor(a1, m); a2 += __shfl_xor(a2, m);
    a3 += __shfl_xor(a3, m); a4 += __shfl_xor(a4, m);
  }
  if (lane == 0) {
    float lg[5] = {a0, a1, a2, a3, a4};
    float mx = lg[0];
    #pragma unroll
    for (int e = 1; e < 5; ++e) mx = fmaxf(mx, lg[e]);
    float ex[5], ssum = 0.f;
    #pragma unroll
    for (int e = 0; e < 5; ++e) { ex[e] = expf(lg[e] - mx); ssum += ex[e]; }
    float raw[5];
    #pragma unroll
    for (int e = 0; e < 5; ++e) raw[e] = ex[e] / ssum;
    int i1 = 0; float v1 = raw[0];
    #pragma unroll
    for (int e = 1; e < 5; ++e) if (raw[e] > v1) { v1 = raw[e]; i1 = e; }
    int i2 = 0; float v2 = -1.f;
    #pragma unroll
    for (int e = 0; e < 5; ++e) if (e != i1 && raw[e] > v2) { v2 = raw[e]; i2 = e; }
    float denom = v1 + v2 + 1e-9f;
    float G1 = v1 / denom, G2 = v2 / denom;
    unsigned x0 = 0u, x1 = (unsigned)tok;
    threefry(x0, x1);
    unsigned bits = x0 ^ x1;
    float u = __uint_as_float((bits >> 9) | 0x3F800000u) - 1.0f;
    int kr = (u < G2 / 0.2f) ? 1 : 0;
    e1[tok] = i1; e2[tok] = i2; g1[tok] = G1; g2[tok] = G2; keepr[tok] = kr;
  }
}

// ---------------- Per-group plan: positions + capacity -----------------------
__global__ __launch_bounds__(256) void plan_kernel(
    const int* __restrict__ e1, const int* __restrict__ e2,
    const int* __restrict__ keepr,
    int* __restrict__ slot1, int* __restrict__ slot2, int* __restrict__ tot) {
  int l = blockIdx.x * blockDim.x + threadIdx.x;
  if (l >= kL) return;
  int base = l * 4;
  int e1v[4], e2v[4], kr[4];
  #pragma unroll
  for (int n = 0; n < 4; ++n) {
    e1v[n] = e1[base + n]; e2v[n] = e2[base + n]; kr[n] = keepr[base + n];
  }
  int c1[5] = {0,0,0,0,0};
  int s1[4];
  #pragma unroll
  for (int n = 0; n < 4; ++n) {
    int e = e1v[n];
    int p = 0;
    #pragma unroll
    for (int q = 0; q < 5; ++q) if (q == e) p = c1[q];
    s1[n] = p;
    #pragma unroll
    for (int q = 0; q < 5; ++q) c1[q] += (q == e);
  }
  int run[5] = {0,0,0,0,0};
  int s2[4];
  #pragma unroll
  for (int n = 0; n < 4; ++n) {
    s2[n] = -1;
    if (kr[n]) {
      int e = e2v[n];
      int p = 0;
      #pragma unroll
      for (int q = 0; q < 5; ++q) if (q == e) p = c1[q] + run[q];
      if (p < kCAP) s2[n] = p;
      #pragma unroll
      for (int q = 0; q < 5; ++q) run[q] += (q == e);
    }
  }
  #pragma unroll
  for (int n = 0; n < 4; ++n) { slot1[base + n] = s1[n]; slot2[base + n] = s2[n]; }
  int adm[5] = {0,0,0,0,0};
  #pragma unroll
  for (int n = 0; n < 4; ++n)
    if (s2[n] >= 0) {
      #pragma unroll
      for (int q = 0; q < 5; ++q) adm[q] += (q == e2v[n]);
    }
  #pragma unroll
  for (int q = 0; q < 5; ++q) tot[l * kNE + q] = c1[q] + adm[q];
}

// ---------------- Per-expert exclusive scan of group totals ------------------
__global__ __launch_bounds__(256) void scan_kernel(
    const int* __restrict__ tot, int* __restrict__ gbase, int* __restrict__ cnt) {
  int e = blockIdx.x;
  int t = threadIdx.x;
  int lane = t & 63, w = t >> 6;
  __shared__ int wsum[4];
  __shared__ int carry;
  if (t == 0) carry = 0;
  __syncthreads();
  for (int chunk = 0; chunk < kL / 256; ++chunk) {
    int g = chunk * 256 + t;
    int v = tot[g * kNE + e];
    int inc = v;
    #pragma unroll
    for (int off = 1; off < 64; off <<= 1) {
      int u = __shfl_up(inc, off);
      if (lane >= off) inc += u;
    }
    if (lane == 63) wsum[w] = inc;
    __syncthreads();
    int wb = 0;
    #pragma unroll
    for (int i = 0; i < 4; ++i) wb += (i < w) ? wsum[i] : 0;
    int total = wsum[0] + wsum[1] + wsum[2] + wsum[3];
    gbase[g * kNE + e] = carry + wb + inc - v;
    __syncthreads();
    if (t == 0) carry += total;
    __syncthreads();
  }
  if (t == 0) cnt[e] = carry;
}

__global__ void bases_kernel(const int* __restrict__ cnt, int* __restrict__ base) {
  if (threadIdx.x == 0 && blockIdx.x == 0) {
    int a = 0;
    #pragma unroll
    for (int e = 0; e < kNE; ++e) { base[e] = a; a += cnt[e]; }
  }
}

// ---------------- Row map: token -> expert-buffer rows -----------------------
__global__ __launch_bounds__(256) void rowmap_kernel(
    const int* __restrict__ e1, const int* __restrict__ e2,
    const int* __restrict__ slot1, const int* __restrict__ slot2,
    const int* __restrict__ gbase, const int* __restrict__ ebase,
    int* __restrict__ rowOf1, int* __restrict__ rowOf2,
    int* __restrict__ tokOfRow) {
  int tok = blockIdx.x * blockDim.x + threadIdx.x;
  if (tok >= kT) return;
  int l = tok >> 2;
  int a = e1[tok];
  int r1 = ebase[a] + gbase[l * kNE + a] + slot1[tok];
  rowOf1[tok] = r1;
  tokOfRow[r1] = tok;
  int s2 = slot2[tok];
  int r2 = -1;
  if (s2 >= 0) {
    int bq = e2[tok];
    r2 = ebase[bq] + gbase[l * kNE + bq] + s2;
    tokOfRow[r2] = tok;
  }
  rowOf2[tok] = r2;
}

// ---------------- Final combine: out = x_res + g1*eo[r1] + g2*eo[r2] ---------
__global__ __launch_bounds__(128) void combine_kernel(
    const float* __restrict__ xres, const unsigned short* __restrict__ eo,
    const float* __restrict__ g1, const float* __restrict__ g2,
    const int* __restrict__ rowOf1, const int* __restrict__ rowOf2,
    float* __restrict__ out) {
  int tok = blockIdx.x;
  int t = threadIdx.x;
  float4 o = *(const float4*)(xres + (size_t)tok * kE + t * 4);
  int p1 = rowOf1[tok];
  float G1 = g1[tok];
  ushort4 a = *(const ushort4*)(eo + (size_t)p1 * kE + t * 4);
  o.x += G1 * bf2f(a.x); o.y += G1 * bf2f(a.y);
  o.z += G1 * bf2f(a.z); o.w += G1 * bf2f(a.w);
  int p2 = rowOf2[tok];
  if (p2 >= 0) {
    float G2 = g2[tok];
    ushort4 c = *(const ushort4*)(eo + (size_t)p2 * kE + t * 4);
    o.x += G2 * bf2f(c.x); o.y += G2 * bf2f(c.y);
    o.z += G2 * bf2f(c.z); o.w += G2 * bf2f(c.w);
  }
  *(float4*)(out + (size_t)tok * kE + t * 4) = o;
}

}  // namespace

extern "C" void kernel_launch(void* const* d_in, const int* in_sizes, int n_in,
                              void* d_out, int out_size, void* d_ws, size_t ws_size,
                              hipStream_t stream) {
  (void)in_sizes; (void)n_in; (void)out_size;
  const float* x    = (const float*)d_in[0];
  const float* ln1w = (const float*)d_in[1];
  const float* ln1b = (const float*)d_in[2];
  const float* ln2w = (const float*)d_in[3];
  const float* ln2b = (const float*)d_in[4];
  const float* wqkv = (const float*)d_in[5];
  const float* bqkv = (const float*)d_in[6];
  const float* wo   = (const float*)d_in[7];
  const float* bo   = (const float*)d_in[8];
  const float* wg   = (const float*)d_in[9];
  const float* w1   = (const float*)d_in[10];
  const float* w2   = (const float*)d_in[11];
  float* out = (float*)d_out;

  // ws layout (float units, 33.75M total = 135 MB):
  // fixed:   xres[0,4194304) w1t[4194304,6815744) w2t[6815744,9437184)
  //          wqkvhi[9437184,9830400) wqkvlo[9830400,10223616)
  //          wohi[10223616,10354688) wolo[10354688,10485760)
  //          ints[10485760,10616832)
  // phase A: h1hi[10616832,12713984) h1lo[12713984,14811136)
  //          qkvhi[14811136,21102592) qkvlo[21102592,27394048)
  //          aohi[27394048,29491200) aolo[29491200,31588352)
  // phase B (reuses phase A):
  //          h2 f32 [10616832,14811136) -> eobf after gating/h2bf
  //          h2bf [14811136,16908288)
  //          hmoe [16908288,33685504)
  if (ws_size < (size_t)134742016) return;
  float* ws   = (float*)d_ws;
  float* xres = ws;
  unsigned short* w1t    = (unsigned short*)(ws + 4194304);  // [5][2048][512]
  unsigned short* w2t    = (unsigned short*)(ws + 6815744);  // [5][512][2048]
  unsigned short* wqkvhi = (unsigned short*)(ws + 9437184);
  unsigned short* wqkvlo = (unsigned short*)(ws + 9830400);
  unsigned short* wohi   = (unsigned short*)(ws + 10223616);
  unsigned short* wolo   = (unsigned short*)(ws + 10354688);
  int* ibuf = (int*)(ws + 10485760);
  unsigned short* h1hi  = (unsigned short*)(ws + 10616832);
  unsigned short* h1lo  = (unsigned short*)(ws + 12713984);
  unsigned short* qkvhi = (unsigned short*)(ws + 14811136);
  unsigned short* qkvlo = (unsigned short*)(ws + 21102592);
  unsigned short* aohi  = (unsigned short*)(ws + 27394048);
  unsigned short* aolo  = (unsigned short*)(ws + 29491200);
  float* h2             = ws + 10616832;
  unsigned short* eobf  = (unsigned short*)(ws + 10616832);  // reuses dead h2
  unsigned short* h2bf  = (unsigned short*)(ws + 14811136);
  unsigned short* hmoe  = (unsigned short*)(ws + 16908288);

  int* e1      = ibuf;
  int* e2      = e1 + kT;
  float* g1f   = (float*)(e2 + kT);
  float* g2f   = g1f + kT;
  int* keepr   = (int*)(g2f + kT);
  int* slot1   = keepr + kT;
  int* slot2   = slot1 + kT;
  int* rowOf1  = slot2 + kT;
  int* rowOf2  = rowOf1 + kT;
  int* tot     = rowOf2 + kT;
  int* gbase   = tot + kL * kNE;
  int* tokOfRow= gbase + kL * kNE;
  int* cnt     = tokOfRow + 2 * kT;
  int* ebase   = cnt + 8;

  // 0. weight conversions: w1 [5][512][2048] -> w1t [5][2048][512] bf16;
  //    w2 [5][2048][512] -> w2t [5][512][2048] bf16; qkv/wo split hi/lo.
  tsplit_kernel<<<dim3(32, 8, kNE), 256, 0, stream>>>(w1, w1t, kE, kFF);
  tsplit_kernel<<<dim3(8, 32, kNE), 256, 0, stream>>>(w2, w2t, kFF, kE);
  wsplit_kernel<<<768, 256, 0, stream>>>(wqkv, wqkvhi, wqkvlo, 1536 * kE / 4);
  wsplit_kernel<<<256, 256, 0, stream>>>(wo, wohi, wolo, kE * kE / 4);
  // 1. h1 = LN1(x) -> split hi/lo
  ln_kernel<1><<<kT, 256, 0, stream>>>(x, ln1w, ln1b, nullptr, h1hi, h1lo);
  // 2. qkv = h1 @ Wqkv^T + b  (split-bf16 MFMA) -> split hi/lo
  dsgemm_kernel<0,1><<<dim3(12, 64), 256, 0, stream>>>(
      h1hi, h1lo, wqkvhi, wqkvlo, bqkv, nullptr,
      nullptr, qkvhi, qkvlo, kT, 1536, kE);
  // 3. attention -> split attn_out
  flash_kernel<<<dim3(32, 32, 1), 256, 0, stream>>>(qkvhi, qkvlo, aohi, aolo);
  // 4. x_res = x + attn_out @ Wo^T + bo  (split-bf16 MFMA)
  dsgemm_kernel<1,0><<<dim3(4, 64), 256, 0, stream>>>(
      aohi, aolo, wohi, wolo, bo, x,
      xres, nullptr, nullptr, kT, kE, kE);
  // 5. h2 = LN2(x_res): f32 + plain bf16 fused
  ln_kernel<2><<<kT, 256, 0, stream>>>(xres, ln2w, ln2b, h2, h2bf, nullptr);
  // 6. gating per token
  gating_kernel<<<kL, 256, 0, stream>>>(h2, wg, e1, e2, g1f, g2f, keepr);
  // 7. per-group plan
  plan_kernel<<<kL / 256, 256, 0, stream>>>(e1, e2, keepr, slot1, slot2, tot);
  // 8. per-expert scan; bases; row maps
  scan_kernel<<<kNE, 256, 0, stream>>>(tot, gbase, cnt);
  bases_kernel<<<1, 32, 0, stream>>>(cnt, ebase);
  rowmap_kernel<<<kT / 256, 256, 0, stream>>>(
      e1, e2, slot1, slot2, gbase, ebase, rowOf1, rowOf2, tokOfRow);
  // 9. hmoe = relu(gather(h2bf) @ w1t[e]^T)  (B pre-transposed [N][K])
  moe_mfma_kernel<1,1,kE,kFF><<<dim3(16, 64, kNE), 256, 0, stream>>>(
      h2bf, w1t, hmoe, tokOfRow, cnt, ebase);
  // 10. eo = hmoe @ w2t[e]^T
  moe_mfma_kernel<0,0,kFF,kE><<<dim3(4, 64, kNE), 256, 0, stream>>>(
      hmoe, w2t, eobf, nullptr, cnt, ebase);
  // 11. out = x_res + g1*eo + g2*eo
  combine_kernel<<<kT, 128, 0, stream>>>(
      xres, eobf, g1f, g2f, rowOf1, rowOf2, out);
}